// Round 1
// baseline (1040.171 us; speedup 1.0000x reference)
//
#include <hip/hip_runtime.h>
#include <hip/hip_bf16.h>
#include <math.h>

#define NU   8000
#define NI   16000
#define NN   24000
#define DD   64
#define NL   2
#define NNZS 768000
#define KD   192        // 3 * 64 concat width
#define NCH  10         // column chunks for lse partials
#define ACHUNK 1600     // 16000 / NCH
#define ATILES 25       // ACHUNK / 64

typedef __attribute__((ext_vector_type(8))) short  short8;
typedef __attribute__((ext_vector_type(4))) float  f32x4;

__device__ __forceinline__ unsigned short f2bf(float x) {
    union { float f; unsigned int u; } v; v.f = x;
    unsigned int r = v.u + 0x7fff + ((v.u >> 16) & 1);   // round-nearest-even
    return (unsigned short)(r >> 16);
}

// ---------------- ego = concat(user_emb, item_emb); also bf16 copy into all_emb[:, 0:64]
__global__ void k_concat(const int* __restrict__ uidx, const int* __restrict__ iidx,
                         const float* __restrict__ ue, const float* __restrict__ ie,
                         float* __restrict__ ego, unsigned short* __restrict__ allemb) {
    int t = blockIdx.x * blockDim.x + threadIdx.x;
    if (t >= NN * DD) return;
    int n = t >> 6, d = t & 63;
    float v = (n < NU) ? ue[uidx[n] * DD + d] : ie[iidx[n - NU] * DD + d];
    ego[t] = v;
    allemb[(size_t)n * KD + d] = f2bf(v);
}

// ---------------- side = segment_sum(vals * ego[cols], rows): one wave per edge, lane = dim
__global__ void k_spmm(const int* __restrict__ rows, const int* __restrict__ cols,
                       const float* __restrict__ vals,
                       const float* __restrict__ ego, float* __restrict__ side) {
    int lane = threadIdx.x & 63;
    int wave = (blockIdx.x * blockDim.x + threadIdx.x) >> 6;
    int nw   = (gridDim.x * blockDim.x) >> 6;
    for (int e = wave; e < NNZS; e += nw) {
        int r = rows[e], c = cols[e];
        float v = vals[e];
        atomicAdd(&side[(size_t)r * DD + lane], v * ego[(size_t)c * DD + lane]);
    }
}

// ---------------- ego = leaky(side@gcW^T+gcb) + leaky((ego*side)@biW^T+bib); bf16 copy to all_emb cols
__global__ __launch_bounds__(256) void k_dense(const float* __restrict__ side, float* __restrict__ ego,
                        const float* __restrict__ gcW, const float* __restrict__ gcb,
                        const float* __restrict__ biW, const float* __restrict__ bib,
                        unsigned short* __restrict__ allemb, int colofs) {
    __shared__ float wg[DD * DD];   // transposed: wg[k][o]
    __shared__ float wb[DD * DD];
    int tid = threadIdx.x;
    for (int i = tid; i < DD * DD; i += blockDim.x) {
        int o = i >> 6, k = i & 63;
        wg[k * DD + o] = gcW[i];
        wb[k * DD + o] = biW[i];
    }
    __syncthreads();
    int lane = tid & 63;
    int wave = (blockIdx.x * blockDim.x + tid) >> 6;
    int nw   = (gridDim.x * blockDim.x) >> 6;
    float bg = gcb[lane], bb = bib[lane];
    for (int n = wave; n < NN; n += nw) {
        float s = side[(size_t)n * DD + lane];
        float e = ego[(size_t)n * DD + lane];
        float p = e * s;
        float a1 = bg, a2 = bb;
#pragma unroll
        for (int k = 0; k < DD; ++k) {
            float sk = __shfl(s, k, 64);
            float pk = __shfl(p, k, 64);
            a1 = fmaf(sk, wg[k * DD + lane], a1);
            a2 = fmaf(pk, wb[k * DD + lane], a2);
        }
        a1 = a1 > 0.f ? a1 : 0.01f * a1;
        a2 = a2 > 0.f ? a2 : 0.01f * a2;
        float o = a1 + a2;
        ego[(size_t)n * DD + lane] = o;
        allemb[(size_t)n * KD + colofs + lane] = f2bf(o);
    }
}

// ---------------- kernel A: per-row online (max, sum-exp) partials over a column chunk
// grid (125, NCH), block 128 = 2 waves; each wave: 32 rows x ACHUNK cols
__global__ __launch_bounds__(128) void k_lse_part(const unsigned short* __restrict__ allemb,
                                                  float* __restrict__ pm, float* __restrict__ ps) {
    int lane = threadIdx.x & 63;
    int wave = threadIdx.x >> 6;
    int r0 = blockIdx.x * 64 + wave * 32;
    int c0 = blockIdx.y * ACHUNK;
    const unsigned short* A = allemb;                       // user rows
    const unsigned short* B = allemb + (size_t)NU * KD;     // item rows
    int kofs = (lane >> 4) * 8;

    short8 a[2][6];
#pragma unroll
    for (int mi = 0; mi < 2; ++mi)
#pragma unroll
        for (int kt = 0; kt < 6; ++kt)
            a[mi][kt] = *(const short8*)(A + (size_t)(r0 + mi * 16 + (lane & 15)) * KD + kt * 32 + kofs);

    float m[2][4], s[2][4];
#pragma unroll
    for (int mi = 0; mi < 2; ++mi)
#pragma unroll
        for (int r = 0; r < 4; ++r) { m[mi][r] = -INFINITY; s[mi][r] = 0.f; }

    for (int t = 0; t < ATILES; ++t) {
        int c = c0 + t * 64;
        f32x4 acc[2][4];
#pragma unroll
        for (int mi = 0; mi < 2; ++mi)
#pragma unroll
            for (int nf = 0; nf < 4; ++nf) acc[mi][nf] = (f32x4){0.f, 0.f, 0.f, 0.f};
#pragma unroll
        for (int nf = 0; nf < 4; ++nf) {
            const unsigned short* bp = B + (size_t)(c + nf * 16 + (lane & 15)) * KD + kofs;
#pragma unroll
            for (int kt = 0; kt < 6; ++kt) {
                short8 b = *(const short8*)(bp + kt * 32);
                acc[0][nf] = __builtin_amdgcn_mfma_f32_16x16x32_bf16(a[0][kt], b, acc[0][nf], 0, 0, 0);
                acc[1][nf] = __builtin_amdgcn_mfma_f32_16x16x32_bf16(a[1][kt], b, acc[1][nf], 0, 0, 0);
            }
        }
        // online softmax update; row = (lane>>4)*4 + r within each mi sub-tile
#pragma unroll
        for (int mi = 0; mi < 2; ++mi)
#pragma unroll
            for (int r = 0; r < 4; ++r) {
                float lm = fmaxf(fmaxf(acc[mi][0][r], acc[mi][1][r]),
                                 fmaxf(acc[mi][2][r], acc[mi][3][r]));
#pragma unroll
                for (int off = 1; off < 16; off <<= 1) lm = fmaxf(lm, __shfl_xor(lm, off, 64));
                float nm = fmaxf(m[mi][r], lm);
                float p = __expf(acc[mi][0][r] - nm) + __expf(acc[mi][1][r] - nm) +
                          __expf(acc[mi][2][r] - nm) + __expf(acc[mi][3][r] - nm);
#pragma unroll
                for (int off = 1; off < 16; off <<= 1) p += __shfl_xor(p, off, 64);
                s[mi][r] = s[mi][r] * __expf(m[mi][r] - nm) + p;
                m[mi][r] = nm;
            }
    }
    if ((lane & 15) == 0) {
        int g = lane >> 4;
#pragma unroll
        for (int mi = 0; mi < 2; ++mi)
#pragma unroll
            for (int r = 0; r < 4; ++r) {
                int row = r0 + mi * 16 + g * 4 + r;
                pm[blockIdx.y * NU + row] = m[mi][r];
                ps[blockIdx.y * NU + row] = s[mi][r];
            }
    }
}

// ---------------- combine partials: lse[r] = m + log(sum)
__global__ void k_lse_comb(const float* __restrict__ pm, const float* __restrict__ ps,
                           float* __restrict__ lse) {
    int r = blockIdx.x * blockDim.x + threadIdx.x;
    if (r >= NU) return;
    float m = -INFINITY;
    for (int c = 0; c < NCH; ++c) m = fmaxf(m, pm[c * NU + r]);
    float s = 0.f;
    for (int c = 0; c < NCH; ++c) s += ps[c * NU + r] * __expf(pm[c * NU + r] - m);
    lse[r] = m + __logf(s);
}

// ---------------- kernel B: recompute scores, write out = s - lse[row]
// grid (125, 125), block 256 = 4 waves (M-split); block tile 64 x 128
__global__ __launch_bounds__(256) void k_out(const unsigned short* __restrict__ allemb,
                                             const float* __restrict__ lse, float* __restrict__ out) {
    int lane = threadIdx.x & 63;
    int wave = threadIdx.x >> 6;
    int r0 = blockIdx.x * 64 + wave * 16;
    int c0 = blockIdx.y * 128;
    const unsigned short* A = allemb;
    const unsigned short* B = allemb + (size_t)NU * KD;
    int kofs = (lane >> 4) * 8;

    short8 a[6];
#pragma unroll
    for (int kt = 0; kt < 6; ++kt)
        a[kt] = *(const short8*)(A + (size_t)(r0 + (lane & 15)) * KD + kt * 32 + kofs);

    f32x4 acc[8];
#pragma unroll
    for (int nf = 0; nf < 8; ++nf) acc[nf] = (f32x4){0.f, 0.f, 0.f, 0.f};
#pragma unroll
    for (int nf = 0; nf < 8; ++nf) {
        const unsigned short* bp = B + (size_t)(c0 + nf * 16 + (lane & 15)) * KD + kofs;
#pragma unroll
        for (int kt = 0; kt < 6; ++kt) {
            short8 b = *(const short8*)(bp + kt * 32);
            acc[nf] = __builtin_amdgcn_mfma_f32_16x16x32_bf16(a[kt], b, acc[nf], 0, 0, 0);
        }
    }
    int g = lane >> 4;
    float l4[4];
#pragma unroll
    for (int r = 0; r < 4; ++r) l4[r] = lse[r0 + g * 4 + r];
#pragma unroll
    for (int nf = 0; nf < 8; ++nf) {
        int col = c0 + nf * 16 + (lane & 15);
#pragma unroll
        for (int r = 0; r < 4; ++r) {
            int row = r0 + g * 4 + r;
            out[(size_t)row * NI + col] = acc[nf][r] - l4[r];
        }
    }
}

extern "C" void kernel_launch(void* const* d_in, const int* in_sizes, int n_in,
                              void* d_out, int out_size, void* d_ws, size_t ws_size,
                              hipStream_t stream) {
    const int*   uidx = (const int*)d_in[0];
    const int*   iidx = (const int*)d_in[1];
    const int*   arow = (const int*)d_in[2];
    const int*   acol = (const int*)d_in[3];
    const float* aval = (const float*)d_in[4];
    const float* ue   = (const float*)d_in[5];
    const float* ie   = (const float*)d_in[6];
    const float* gcW  = (const float*)d_in[7];
    const float* gcb  = (const float*)d_in[8];
    const float* biW  = (const float*)d_in[9];
    const float* bib  = (const float*)d_in[10];
    float* out = (float*)d_out;

    char* w = (char*)d_ws;
    float* ego  = (float*)w;                      w += (size_t)NN * DD * sizeof(float);
    float* side = (float*)w;                      w += (size_t)NN * DD * sizeof(float);
    unsigned short* allemb = (unsigned short*)w;  w += (size_t)NN * KD * sizeof(unsigned short);
    float* pm  = (float*)w;                       w += (size_t)NCH * NU * sizeof(float);
    float* ps  = (float*)w;                       w += (size_t)NCH * NU * sizeof(float);
    float* lse = (float*)w;                       w += (size_t)NU * sizeof(float);

    k_concat<<<(NN * DD + 255) / 256, 256, 0, stream>>>(uidx, iidx, ue, ie, ego, allemb);

    for (int l = 0; l < NL; ++l) {
        hipMemsetAsync(side, 0, (size_t)NN * DD * sizeof(float), stream);
        k_spmm<<<2048, 256, 0, stream>>>(arow, acol, aval, ego, side);
        k_dense<<<512, 256, 0, stream>>>(side, ego, gcW + l * DD * DD, gcb + l * DD,
                                         biW + l * DD * DD, bib + l * DD, allemb, (l + 1) * DD);
    }

    k_lse_part<<<dim3(125, NCH), 128, 0, stream>>>(allemb, pm, ps);
    k_lse_comb<<<(NU + 255) / 256, 256, 0, stream>>>(pm, ps, lse);
    k_out<<<dim3(125, 125), 256, 0, stream>>>(allemb, lse, out);
}

// Round 2
// 910.844 us; speedup vs baseline: 1.1420x; 1.1420x over previous
//
#include <hip/hip_runtime.h>
#include <hip/hip_bf16.h>
#include <math.h>

#define NU   8000
#define NI   16000
#define NN   24000
#define DD   64
#define NL   2
#define NNZS 768000
#define KD   192        // 3 * 64 concat width
#define NCH  25         // column chunks for lse partials
#define ACHUNK 640      // 16000 / NCH
#define CTILES 5        // ACHUNK / 128

typedef __attribute__((ext_vector_type(8))) short  short8;
typedef __attribute__((ext_vector_type(4))) float  f32x4;

__device__ __forceinline__ unsigned short f2bf(float x) {
    union { float f; unsigned int u; } v; v.f = x;
    unsigned int r = v.u + 0x7fff + ((v.u >> 16) & 1);   // round-nearest-even
    return (unsigned short)(r >> 16);
}

// ---------------- ego = concat(user_emb, item_emb); also bf16 copy into all_emb[:, 0:64]
__global__ void k_concat(const int* __restrict__ uidx, const int* __restrict__ iidx,
                         const float* __restrict__ ue, const float* __restrict__ ie,
                         float* __restrict__ ego, unsigned short* __restrict__ allemb) {
    int t = blockIdx.x * blockDim.x + threadIdx.x;
    if (t >= NN * DD) return;
    int n = t >> 6, d = t & 63;
    float v = (n < NU) ? ue[uidx[n] * DD + d] : ie[iidx[n - NU] * DD + d];
    ego[t] = v;
    allemb[(size_t)n * KD + d] = f2bf(v);
}

// ---------------- side = segment_sum(vals * ego[cols], rows): one wave per edge, lane = dim
__global__ void k_spmm(const int* __restrict__ rows, const int* __restrict__ cols,
                       const float* __restrict__ vals,
                       const float* __restrict__ ego, float* __restrict__ side) {
    int lane = threadIdx.x & 63;
    int wave = (blockIdx.x * blockDim.x + threadIdx.x) >> 6;
    int nw   = (gridDim.x * blockDim.x) >> 6;
    for (int e = wave; e < NNZS; e += nw) {
        int r = rows[e], c = cols[e];
        float v = vals[e];
        atomicAdd(&side[(size_t)r * DD + lane], v * ego[(size_t)c * DD + lane]);
    }
}

// ---------------- ego = leaky(side@gcW^T+gcb) + leaky((ego*side)@biW^T+bib); bf16 copy to all_emb cols
__global__ __launch_bounds__(256) void k_dense(const float* __restrict__ side, float* __restrict__ ego,
                        const float* __restrict__ gcW, const float* __restrict__ gcb,
                        const float* __restrict__ biW, const float* __restrict__ bib,
                        unsigned short* __restrict__ allemb, int colofs) {
    __shared__ float wg[DD * DD];   // transposed: wg[k][o]
    __shared__ float wb[DD * DD];
    int tid = threadIdx.x;
    for (int i = tid; i < DD * DD; i += blockDim.x) {
        int o = i >> 6, k = i & 63;
        wg[k * DD + o] = gcW[i];
        wb[k * DD + o] = biW[i];
    }
    __syncthreads();
    int lane = tid & 63;
    int wave = (blockIdx.x * blockDim.x + tid) >> 6;
    int nw   = (gridDim.x * blockDim.x) >> 6;
    float bg = gcb[lane], bb = bib[lane];
    for (int n = wave; n < NN; n += nw) {
        float s = side[(size_t)n * DD + lane];
        float e = ego[(size_t)n * DD + lane];
        float p = e * s;
        float a1 = bg, a2 = bb;
#pragma unroll
        for (int k = 0; k < DD; ++k) {
            float sk = __shfl(s, k, 64);
            float pk = __shfl(p, k, 64);
            a1 = fmaf(sk, wg[k * DD + lane], a1);
            a2 = fmaf(pk, wb[k * DD + lane], a2);
        }
        a1 = a1 > 0.f ? a1 : 0.01f * a1;
        a2 = a2 > 0.f ? a2 : 0.01f * a2;
        float o = a1 + a2;
        ego[(size_t)n * DD + lane] = o;
        allemb[(size_t)n * KD + colofs + lane] = f2bf(o);
    }
}

// ---------------- kernel A: per-row online (max, sum-exp) partials over a 640-col chunk
// grid (125, NCH), block 128 = 2 waves; each wave: 32 rows; block: 64 rows x 640 cols
// lane-local online state (each lane owns cols == lane&15 mod 16); cross-lane merge ONCE at end.
__global__ __launch_bounds__(128) void k_lse_part(const unsigned short* __restrict__ allemb,
                                                  float* __restrict__ pm, float* __restrict__ ps) {
    int lane = threadIdx.x & 63;
    int wave = threadIdx.x >> 6;
    int r0 = blockIdx.x * 64 + wave * 32;
    int c0 = blockIdx.y * ACHUNK;
    const unsigned short* A = allemb;                       // user rows
    const unsigned short* B = allemb + (size_t)NU * KD;     // item rows
    int kofs = (lane >> 4) * 8;

    short8 a[2][6];
#pragma unroll
    for (int mi = 0; mi < 2; ++mi)
#pragma unroll
        for (int kt = 0; kt < 6; ++kt)
            a[mi][kt] = *(const short8*)(A + (size_t)(r0 + mi * 16 + (lane & 15)) * KD + kt * 32 + kofs);

    float m[2][4], s[2][4];
#pragma unroll
    for (int mi = 0; mi < 2; ++mi)
#pragma unroll
        for (int r = 0; r < 4; ++r) { m[mi][r] = -INFINITY; s[mi][r] = 0.f; }

    for (int t = 0; t < CTILES; ++t) {
        int c = c0 + t * 128;
        f32x4 acc[2][8];
#pragma unroll
        for (int mi = 0; mi < 2; ++mi)
#pragma unroll
            for (int nf = 0; nf < 8; ++nf) acc[mi][nf] = (f32x4){0.f, 0.f, 0.f, 0.f};
#pragma unroll
        for (int nf = 0; nf < 8; ++nf) {
            const unsigned short* bp = B + (size_t)(c + nf * 16 + (lane & 15)) * KD + kofs;
#pragma unroll
            for (int kt = 0; kt < 6; ++kt) {
                short8 b = *(const short8*)(bp + kt * 32);
                acc[0][nf] = __builtin_amdgcn_mfma_f32_16x16x32_bf16(a[0][kt], b, acc[0][nf], 0, 0, 0);
                acc[1][nf] = __builtin_amdgcn_mfma_f32_16x16x32_bf16(a[1][kt], b, acc[1][nf], 0, 0, 0);
            }
        }
        // lane-local online update: no cross-lane ops in the loop
#pragma unroll
        for (int mi = 0; mi < 2; ++mi)
#pragma unroll
            for (int r = 0; r < 4; ++r) {
                float lm = acc[mi][0][r];
#pragma unroll
                for (int nf = 1; nf < 8; ++nf) lm = fmaxf(lm, acc[mi][nf][r]);
                float nm = fmaxf(m[mi][r], lm);
                float p = 0.f;
#pragma unroll
                for (int nf = 0; nf < 8; ++nf) p += __expf(acc[mi][nf][r] - nm);
                s[mi][r] = s[mi][r] * __expf(m[mi][r] - nm) + p;
                m[mi][r] = nm;
            }
    }
    // merge the 16 lanes of each group (offsets < 16 stay within the group)
#pragma unroll
    for (int mi = 0; mi < 2; ++mi)
#pragma unroll
        for (int r = 0; r < 4; ++r) {
            float mm = m[mi][r], ss = s[mi][r];
#pragma unroll
            for (int off = 1; off < 16; off <<= 1) {
                float om = __shfl_xor(mm, off, 64);
                float os = __shfl_xor(ss, off, 64);
                float nm = fmaxf(mm, om);
                ss = ss * __expf(mm - nm) + os * __expf(om - nm);
                mm = nm;
            }
            m[mi][r] = mm; s[mi][r] = ss;
        }
    if ((lane & 15) == 0) {
        int g = lane >> 4;
#pragma unroll
        for (int mi = 0; mi < 2; ++mi)
#pragma unroll
            for (int r = 0; r < 4; ++r) {
                int row = r0 + mi * 16 + g * 4 + r;
                pm[blockIdx.y * NU + row] = m[mi][r];
                ps[blockIdx.y * NU + row] = s[mi][r];
            }
    }
}

// ---------------- combine partials: lse[r] = m + log(sum)
__global__ void k_lse_comb(const float* __restrict__ pm, const float* __restrict__ ps,
                           float* __restrict__ lse) {
    int r = blockIdx.x * blockDim.x + threadIdx.x;
    if (r >= NU) return;
    float m = -INFINITY;
    for (int c = 0; c < NCH; ++c) m = fmaxf(m, pm[c * NU + r]);
    float s = 0.f;
    for (int c = 0; c < NCH; ++c) s += ps[c * NU + r] * __expf(pm[c * NU + r] - m);
    lse[r] = m + __logf(s);
}

// ---------------- kernel B: recompute scores, write out = s - lse[row]
// grid (63, 125), block 256 = 4 waves (rows split 4 x 32); block tile 128 x 128
// epilogue: LDS-stage 16x128 per wave (row pad 132 -> 2-way bank alias, free),
// then coalesced float4 stores (2 rows x 512B per instruction).
__global__ __launch_bounds__(256) void k_out(const unsigned short* __restrict__ allemb,
                                             const float* __restrict__ lse, float* __restrict__ out) {
    __shared__ float tile[4][16][132];
    int lane = threadIdx.x & 63;
    int wave = threadIdx.x >> 6;
    int r0 = blockIdx.x * 128 + wave * 32;
    int c0 = blockIdx.y * 128;
    const unsigned short* A = allemb;
    const unsigned short* B = allemb + (size_t)NU * KD;
    int kofs = (lane >> 4) * 8;
    int g = lane >> 4;

    short8 a[2][6];
#pragma unroll
    for (int mi = 0; mi < 2; ++mi) {
        int ar = r0 + mi * 16 + (lane & 15);
        if (ar > NU - 1) ar = NU - 1;   // ragged row guard (last block)
#pragma unroll
        for (int kt = 0; kt < 6; ++kt)
            a[mi][kt] = *(const short8*)(A + (size_t)ar * KD + kt * 32 + kofs);
    }

    f32x4 acc[2][8];
#pragma unroll
    for (int mi = 0; mi < 2; ++mi)
#pragma unroll
        for (int nf = 0; nf < 8; ++nf) acc[mi][nf] = (f32x4){0.f, 0.f, 0.f, 0.f};
#pragma unroll
    for (int nf = 0; nf < 8; ++nf) {
        const unsigned short* bp = B + (size_t)(c0 + nf * 16 + (lane & 15)) * KD + kofs;
#pragma unroll
        for (int kt = 0; kt < 6; ++kt) {
            short8 b = *(const short8*)(bp + kt * 32);
            acc[0][nf] = __builtin_amdgcn_mfma_f32_16x16x32_bf16(a[0][kt], b, acc[0][nf], 0, 0, 0);
            acc[1][nf] = __builtin_amdgcn_mfma_f32_16x16x32_bf16(a[1][kt], b, acc[1][nf], 0, 0, 0);
        }
    }

    float l4[2][4];
#pragma unroll
    for (int mi = 0; mi < 2; ++mi)
#pragma unroll
        for (int r = 0; r < 4; ++r) {
            int row = r0 + mi * 16 + g * 4 + r;
            l4[mi][r] = lse[row > NU - 1 ? NU - 1 : row];
        }

#pragma unroll
    for (int mi = 0; mi < 2; ++mi) {
        int rowbase = r0 + mi * 16;
        // stage into LDS (wave-private buffer; no __syncthreads needed)
#pragma unroll
        for (int nf = 0; nf < 8; ++nf)
#pragma unroll
            for (int r = 0; r < 4; ++r)
                tile[wave][g * 4 + r][nf * 16 + (lane & 15)] = acc[mi][nf][r] - l4[mi][r];
        // coalesced read-back + store: 512 float4 over 8 iterations
#pragma unroll
        for (int it = 0; it < 8; ++it) {
            int idx = it * 64 + lane;
            int rr = idx >> 5;
            int cc = (idx & 31) * 4;
            int row = rowbase + rr;
            if (row < NU) {
                f32x4 v = *(const f32x4*)&tile[wave][rr][cc];
                *(f32x4*)&out[(size_t)row * NI + c0 + cc] = v;
            }
        }
    }
}

extern "C" void kernel_launch(void* const* d_in, const int* in_sizes, int n_in,
                              void* d_out, int out_size, void* d_ws, size_t ws_size,
                              hipStream_t stream) {
    const int*   uidx = (const int*)d_in[0];
    const int*   iidx = (const int*)d_in[1];
    const int*   arow = (const int*)d_in[2];
    const int*   acol = (const int*)d_in[3];
    const float* aval = (const float*)d_in[4];
    const float* ue   = (const float*)d_in[5];
    const float* ie   = (const float*)d_in[6];
    const float* gcW  = (const float*)d_in[7];
    const float* gcb  = (const float*)d_in[8];
    const float* biW  = (const float*)d_in[9];
    const float* bib  = (const float*)d_in[10];
    float* out = (float*)d_out;

    char* w = (char*)d_ws;
    float* ego  = (float*)w;                      w += (size_t)NN * DD * sizeof(float);
    float* side = (float*)w;                      w += (size_t)NN * DD * sizeof(float);
    unsigned short* allemb = (unsigned short*)w;  w += (size_t)NN * KD * sizeof(unsigned short);
    float* pm  = (float*)w;                       w += (size_t)NCH * NU * sizeof(float);
    float* ps  = (float*)w;                       w += (size_t)NCH * NU * sizeof(float);
    float* lse = (float*)w;                       w += (size_t)NU * sizeof(float);

    k_concat<<<(NN * DD + 255) / 256, 256, 0, stream>>>(uidx, iidx, ue, ie, ego, allemb);

    for (int l = 0; l < NL; ++l) {
        hipMemsetAsync(side, 0, (size_t)NN * DD * sizeof(float), stream);
        k_spmm<<<2048, 256, 0, stream>>>(arow, acol, aval, ego, side);
        k_dense<<<512, 256, 0, stream>>>(side, ego, gcW + l * DD * DD, gcb + l * DD,
                                         biW + l * DD * DD, bib + l * DD, allemb, (l + 1) * DD);
    }

    k_lse_part<<<dim3(125, NCH), 128, 0, stream>>>(allemb, pm, ps);
    k_lse_comb<<<(NU + 255) / 256, 256, 0, stream>>>(pm, ps, lse);
    k_out<<<dim3(63, 125), 256, 0, stream>>>(allemb, lse, out);
}

// Round 3
// 771.904 us; speedup vs baseline: 1.3475x; 1.1800x over previous
//
#include <hip/hip_runtime.h>
#include <hip/hip_bf16.h>
#include <math.h>

#define NU   8000
#define NI   16000
#define NN   24000
#define DD   64
#define NL   2
#define NNZS 768000
#define KD   192        // 3 * 64 concat width
#define NCH  25         // column chunks for lse partials
#define ACHUNK 640      // 16000 / NCH
#define CTILES 5        // ACHUNK / 128

typedef __attribute__((ext_vector_type(8))) short  short8;
typedef __attribute__((ext_vector_type(4))) float  f32x4;

__device__ __forceinline__ unsigned short f2bf(float x) {
    union { float f; unsigned int u; } v; v.f = x;
    unsigned int r = v.u + 0x7fff + ((v.u >> 16) & 1);   // round-nearest-even
    return (unsigned short)(r >> 16);
}

// ---------------- ego = concat(user_emb, item_emb); also bf16 copy into all_emb[:, 0:64]
__global__ void k_concat(const int* __restrict__ uidx, const int* __restrict__ iidx,
                         const float* __restrict__ ue, const float* __restrict__ ie,
                         float* __restrict__ ego, unsigned short* __restrict__ allemb) {
    int t = blockIdx.x * blockDim.x + threadIdx.x;
    if (t >= NN * DD) return;
    int n = t >> 6, d = t & 63;
    float v = (n < NU) ? ue[uidx[n] * DD + d] : ie[iidx[n - NU] * DD + d];
    ego[t] = v;
    allemb[(size_t)n * KD + d] = f2bf(v);
}

// ---------------- CSR build: histogram -> scan -> scatter (once per launch)
__global__ void k_hist(const int* __restrict__ rows, int* __restrict__ cnt) {
    int e = blockIdx.x * blockDim.x + threadIdx.x;
    if (e < NNZS) atomicAdd(&cnt[rows[e]], 1);
}

__global__ __launch_bounds__(1024) void k_scan(const int* __restrict__ cnt,
                                               int* __restrict__ rp, int* __restrict__ wp) {
    __shared__ int buf[1024];
    __shared__ int carry;
    int tid = threadIdx.x;
    if (tid == 0) { carry = 0; rp[0] = 0; }
    __syncthreads();
    for (int base = 0; base < NN; base += 1024) {
        int i = base + tid;
        int v = (i < NN) ? cnt[i] : 0;
        buf[tid] = v;
        __syncthreads();
#pragma unroll
        for (int off = 1; off < 1024; off <<= 1) {
            int t = (tid >= off) ? buf[tid - off] : 0;
            __syncthreads();
            buf[tid] += t;
            __syncthreads();
        }
        int incl  = buf[tid];
        int total = buf[1023];
        int g = carry + incl;
        if (i < NN) { rp[i + 1] = g; wp[i] = g - v; }
        __syncthreads();
        if (tid == 0) carry += total;
        __syncthreads();
    }
}

__global__ void k_scatter(const int* __restrict__ rows, const int* __restrict__ cols,
                          const float* __restrict__ vals, int* __restrict__ wp,
                          int* __restrict__ scol, float* __restrict__ sval) {
    int e = blockIdx.x * blockDim.x + threadIdx.x;
    if (e >= NNZS) return;
    int r = rows[e];
    int pos = atomicAdd(&wp[r], 1);
    scol[pos] = cols[e];
    sval[pos] = vals[e];
}

// ---------------- side[r] = sum_e val_e * ego[col_e]: one wave per row, lane = dim, no atomics
__global__ void k_spmm_csr(const int* __restrict__ rp, const int* __restrict__ scol,
                           const float* __restrict__ sval,
                           const float* __restrict__ ego, float* __restrict__ side) {
    int lane = threadIdx.x & 63;
    int wave = (blockIdx.x * blockDim.x + threadIdx.x) >> 6;
    int nw   = (gridDim.x * blockDim.x) >> 6;
    for (int r = wave; r < NN; r += nw) {
        int e0 = rp[r], e1 = rp[r + 1];
        float acc = 0.f;
        int e = e0;
        for (; e + 4 <= e1; e += 4) {
            int   c0 = scol[e],     c1 = scol[e + 1], c2 = scol[e + 2], c3 = scol[e + 3];
            float v0 = sval[e],     v1 = sval[e + 1], v2 = sval[e + 2], v3 = sval[e + 3];
            acc = fmaf(v0, ego[(size_t)c0 * DD + lane], acc);
            acc = fmaf(v1, ego[(size_t)c1 * DD + lane], acc);
            acc = fmaf(v2, ego[(size_t)c2 * DD + lane], acc);
            acc = fmaf(v3, ego[(size_t)c3 * DD + lane], acc);
        }
        for (; e < e1; ++e)
            acc = fmaf(sval[e], ego[(size_t)scol[e] * DD + lane], acc);
        side[(size_t)r * DD + lane] = acc;
    }
}

// ---------------- ego = leaky(side@gcW^T+gcb) + leaky((ego*side)@biW^T+bib); bf16 copy to all_emb cols
__global__ __launch_bounds__(256) void k_dense(const float* __restrict__ side, float* __restrict__ ego,
                        const float* __restrict__ gcW, const float* __restrict__ gcb,
                        const float* __restrict__ biW, const float* __restrict__ bib,
                        unsigned short* __restrict__ allemb, int colofs) {
    __shared__ float wg[DD * DD];   // transposed: wg[k][o]
    __shared__ float wb[DD * DD];
    int tid = threadIdx.x;
    for (int i = tid; i < DD * DD; i += blockDim.x) {
        int o = i >> 6, k = i & 63;
        wg[k * DD + o] = gcW[i];
        wb[k * DD + o] = biW[i];
    }
    __syncthreads();
    int lane = tid & 63;
    int wave = (blockIdx.x * blockDim.x + tid) >> 6;
    int nw   = (gridDim.x * blockDim.x) >> 6;
    float bg = gcb[lane], bb = bib[lane];
    for (int n = wave; n < NN; n += nw) {
        float s = side[(size_t)n * DD + lane];
        float e = ego[(size_t)n * DD + lane];
        float p = e * s;
        float a1 = bg, a2 = bb;
#pragma unroll
        for (int k = 0; k < DD; ++k) {
            float sk = __shfl(s, k, 64);
            float pk = __shfl(p, k, 64);
            a1 = fmaf(sk, wg[k * DD + lane], a1);
            a2 = fmaf(pk, wb[k * DD + lane], a2);
        }
        a1 = a1 > 0.f ? a1 : 0.01f * a1;
        a2 = a2 > 0.f ? a2 : 0.01f * a2;
        float o = a1 + a2;
        ego[(size_t)n * DD + lane] = o;
        allemb[(size_t)n * KD + colofs + lane] = f2bf(o);
    }
}

// ---------------- kernel A: per-row online (max, sum-exp) partials over a 640-col chunk
// grid (125, NCH), block 128 = 2 waves; lane-local online state, cross-lane merge once at end.
__global__ __launch_bounds__(128) void k_lse_part(const unsigned short* __restrict__ allemb,
                                                  float* __restrict__ pm, float* __restrict__ ps) {
    int lane = threadIdx.x & 63;
    int wave = threadIdx.x >> 6;
    int r0 = blockIdx.x * 64 + wave * 32;
    int c0 = blockIdx.y * ACHUNK;
    const unsigned short* A = allemb;                       // user rows
    const unsigned short* B = allemb + (size_t)NU * KD;     // item rows
    int kofs = (lane >> 4) * 8;

    short8 a[2][6];
#pragma unroll
    for (int mi = 0; mi < 2; ++mi)
#pragma unroll
        for (int kt = 0; kt < 6; ++kt)
            a[mi][kt] = *(const short8*)(A + (size_t)(r0 + mi * 16 + (lane & 15)) * KD + kt * 32 + kofs);

    float m[2][4], s[2][4];
#pragma unroll
    for (int mi = 0; mi < 2; ++mi)
#pragma unroll
        for (int r = 0; r < 4; ++r) { m[mi][r] = -INFINITY; s[mi][r] = 0.f; }

    for (int t = 0; t < CTILES; ++t) {
        int c = c0 + t * 128;
        f32x4 acc[2][8];
#pragma unroll
        for (int mi = 0; mi < 2; ++mi)
#pragma unroll
            for (int nf = 0; nf < 8; ++nf) acc[mi][nf] = (f32x4){0.f, 0.f, 0.f, 0.f};
#pragma unroll
        for (int nf = 0; nf < 8; ++nf) {
            const unsigned short* bp = B + (size_t)(c + nf * 16 + (lane & 15)) * KD + kofs;
#pragma unroll
            for (int kt = 0; kt < 6; ++kt) {
                short8 b = *(const short8*)(bp + kt * 32);
                acc[0][nf] = __builtin_amdgcn_mfma_f32_16x16x32_bf16(a[0][kt], b, acc[0][nf], 0, 0, 0);
                acc[1][nf] = __builtin_amdgcn_mfma_f32_16x16x32_bf16(a[1][kt], b, acc[1][nf], 0, 0, 0);
            }
        }
#pragma unroll
        for (int mi = 0; mi < 2; ++mi)
#pragma unroll
            for (int r = 0; r < 4; ++r) {
                float lm = acc[mi][0][r];
#pragma unroll
                for (int nf = 1; nf < 8; ++nf) lm = fmaxf(lm, acc[mi][nf][r]);
                float nm = fmaxf(m[mi][r], lm);
                float p = 0.f;
#pragma unroll
                for (int nf = 0; nf < 8; ++nf) p += __expf(acc[mi][nf][r] - nm);
                s[mi][r] = s[mi][r] * __expf(m[mi][r] - nm) + p;
                m[mi][r] = nm;
            }
    }
#pragma unroll
    for (int mi = 0; mi < 2; ++mi)
#pragma unroll
        for (int r = 0; r < 4; ++r) {
            float mm = m[mi][r], ss = s[mi][r];
#pragma unroll
            for (int off = 1; off < 16; off <<= 1) {
                float om = __shfl_xor(mm, off, 64);
                float os = __shfl_xor(ss, off, 64);
                float nm = fmaxf(mm, om);
                ss = ss * __expf(mm - nm) + os * __expf(om - nm);
                mm = nm;
            }
            m[mi][r] = mm; s[mi][r] = ss;
        }
    if ((lane & 15) == 0) {
        int g = lane >> 4;
#pragma unroll
        for (int mi = 0; mi < 2; ++mi)
#pragma unroll
            for (int r = 0; r < 4; ++r) {
                int row = r0 + mi * 16 + g * 4 + r;
                pm[blockIdx.y * NU + row] = m[mi][r];
                ps[blockIdx.y * NU + row] = s[mi][r];
            }
    }
}

// ---------------- combine partials: lse[r] = m + log(sum)
__global__ void k_lse_comb(const float* __restrict__ pm, const float* __restrict__ ps,
                           float* __restrict__ lse) {
    int r = blockIdx.x * blockDim.x + threadIdx.x;
    if (r >= NU) return;
    float m = -INFINITY;
    for (int c = 0; c < NCH; ++c) m = fmaxf(m, pm[c * NU + r]);
    float s = 0.f;
    for (int c = 0; c < NCH; ++c) s += ps[c * NU + r] * __expf(pm[c * NU + r] - m);
    lse[r] = m + __logf(s);
}

// ---------------- kernel B: recompute scores, write out = s - lse[row]
// grid (63, 125), block 256 = 4 waves; block tile 128 x 128; LDS-staged coalesced stores
__global__ __launch_bounds__(256) void k_out(const unsigned short* __restrict__ allemb,
                                             const float* __restrict__ lse, float* __restrict__ out) {
    __shared__ float tile[4][16][132];
    int lane = threadIdx.x & 63;
    int wave = threadIdx.x >> 6;
    int r0 = blockIdx.x * 128 + wave * 32;
    int c0 = blockIdx.y * 128;
    const unsigned short* A = allemb;
    const unsigned short* B = allemb + (size_t)NU * KD;
    int kofs = (lane >> 4) * 8;
    int g = lane >> 4;

    short8 a[2][6];
#pragma unroll
    for (int mi = 0; mi < 2; ++mi) {
        int ar = r0 + mi * 16 + (lane & 15);
        if (ar > NU - 1) ar = NU - 1;   // ragged row guard (last block)
#pragma unroll
        for (int kt = 0; kt < 6; ++kt)
            a[mi][kt] = *(const short8*)(A + (size_t)ar * KD + kt * 32 + kofs);
    }

    f32x4 acc[2][8];
#pragma unroll
    for (int mi = 0; mi < 2; ++mi)
#pragma unroll
        for (int nf = 0; nf < 8; ++nf) acc[mi][nf] = (f32x4){0.f, 0.f, 0.f, 0.f};
#pragma unroll
    for (int nf = 0; nf < 8; ++nf) {
        const unsigned short* bp = B + (size_t)(c0 + nf * 16 + (lane & 15)) * KD + kofs;
#pragma unroll
        for (int kt = 0; kt < 6; ++kt) {
            short8 b = *(const short8*)(bp + kt * 32);
            acc[0][nf] = __builtin_amdgcn_mfma_f32_16x16x32_bf16(a[0][kt], b, acc[0][nf], 0, 0, 0);
            acc[1][nf] = __builtin_amdgcn_mfma_f32_16x16x32_bf16(a[1][kt], b, acc[1][nf], 0, 0, 0);
        }
    }

    float l4[2][4];
#pragma unroll
    for (int mi = 0; mi < 2; ++mi)
#pragma unroll
        for (int r = 0; r < 4; ++r) {
            int row = r0 + mi * 16 + g * 4 + r;
            l4[mi][r] = lse[row > NU - 1 ? NU - 1 : row];
        }

#pragma unroll
    for (int mi = 0; mi < 2; ++mi) {
        int rowbase = r0 + mi * 16;
#pragma unroll
        for (int nf = 0; nf < 8; ++nf)
#pragma unroll
            for (int r = 0; r < 4; ++r)
                tile[wave][g * 4 + r][nf * 16 + (lane & 15)] = acc[mi][nf][r] - l4[mi][r];
#pragma unroll
        for (int it = 0; it < 8; ++it) {
            int idx = it * 64 + lane;
            int rr = idx >> 5;
            int cc = (idx & 31) * 4;
            int row = rowbase + rr;
            if (row < NU) {
                f32x4 v = *(const f32x4*)&tile[wave][rr][cc];
                *(f32x4*)&out[(size_t)row * NI + c0 + cc] = v;
            }
        }
    }
}

extern "C" void kernel_launch(void* const* d_in, const int* in_sizes, int n_in,
                              void* d_out, int out_size, void* d_ws, size_t ws_size,
                              hipStream_t stream) {
    const int*   uidx = (const int*)d_in[0];
    const int*   iidx = (const int*)d_in[1];
    const int*   arow = (const int*)d_in[2];
    const int*   acol = (const int*)d_in[3];
    const float* aval = (const float*)d_in[4];
    const float* ue   = (const float*)d_in[5];
    const float* ie   = (const float*)d_in[6];
    const float* gcW  = (const float*)d_in[7];
    const float* gcb  = (const float*)d_in[8];
    const float* biW  = (const float*)d_in[9];
    const float* bib  = (const float*)d_in[10];
    float* out = (float*)d_out;

    char* w = (char*)d_ws;
    float* ego  = (float*)w;                      w += (size_t)NN * DD * sizeof(float);
    float* side = (float*)w;                      w += (size_t)NN * DD * sizeof(float);
    unsigned short* allemb = (unsigned short*)w;  w += (size_t)NN * KD * sizeof(unsigned short);
    float* pm  = (float*)w;                       w += (size_t)NCH * NU * sizeof(float);
    float* ps  = (float*)w;                       w += (size_t)NCH * NU * sizeof(float);
    float* lse = (float*)w;                       w += (size_t)NU * sizeof(float);
    int* cnt   = (int*)w;                         w += (size_t)NN * sizeof(int);
    int* rp    = (int*)w;                         w += (size_t)(NN + 1) * sizeof(int);
    int* wp    = (int*)w;                         w += (size_t)NN * sizeof(int);
    int* scol  = (int*)w;                         w += (size_t)NNZS * sizeof(int);
    float* sval = (float*)w;                      w += (size_t)NNZS * sizeof(float);

    k_concat<<<(NN * DD + 255) / 256, 256, 0, stream>>>(uidx, iidx, ue, ie, ego, allemb);

    // CSR build (shared by both layers)
    hipMemsetAsync(cnt, 0, (size_t)NN * sizeof(int), stream);
    k_hist<<<(NNZS + 255) / 256, 256, 0, stream>>>(arow, cnt);
    k_scan<<<1, 1024, 0, stream>>>(cnt, rp, wp);
    k_scatter<<<(NNZS + 255) / 256, 256, 0, stream>>>(arow, acol, aval, wp, scol, sval);

    for (int l = 0; l < NL; ++l) {
        k_spmm_csr<<<3000, 256, 0, stream>>>(rp, scol, sval, ego, side);
        k_dense<<<512, 256, 0, stream>>>(side, ego, gcW + l * DD * DD, gcb + l * DD,
                                         biW + l * DD * DD, bib + l * DD, allemb, (l + 1) * DD);
    }

    k_lse_part<<<dim3(125, NCH), 128, 0, stream>>>(allemb, pm, ps);
    k_lse_comb<<<(NU + 255) / 256, 256, 0, stream>>>(pm, ps, lse);
    k_out<<<dim3(63, 125), 256, 0, stream>>>(allemb, lse, out);
}

// Round 4
// 752.342 us; speedup vs baseline: 1.3826x; 1.0260x over previous
//
#include <hip/hip_runtime.h>
#include <hip/hip_bf16.h>
#include <math.h>

#define NU   8000
#define NI   16000
#define NN   24000
#define DD   64
#define NL   2
#define NNZS 768000
#define KD   192        // 3 * 64 concat width
#define NCH  25         // column chunks for lse partials
#define ACHUNK 640      // 16000 / NCH
#define CTILES 5        // ACHUNK / 128
#define RBLK 63         // ceil(8000/128) row blocks for both GEMMs

typedef __attribute__((ext_vector_type(8))) short  short8;
typedef __attribute__((ext_vector_type(4))) float  f32x4;

__device__ __forceinline__ unsigned short f2bf(float x) {
    union { float f; unsigned int u; } v; v.f = x;
    unsigned int r = v.u + 0x7fff + ((v.u >> 16) & 1);   // round-nearest-even
    return (unsigned short)(r >> 16);
}

// ---------------- ego = concat(user_emb, item_emb); also bf16 copy into all_emb[:, 0:64]
__global__ void k_concat(const int* __restrict__ uidx, const int* __restrict__ iidx,
                         const float* __restrict__ ue, const float* __restrict__ ie,
                         float* __restrict__ ego, unsigned short* __restrict__ allemb) {
    int t = blockIdx.x * blockDim.x + threadIdx.x;
    if (t >= NN * DD) return;
    int n = t >> 6, d = t & 63;
    float v = (n < NU) ? ue[uidx[n] * DD + d] : ie[iidx[n - NU] * DD + d];
    ego[t] = v;
    allemb[(size_t)n * KD + d] = f2bf(v);
}

// ---------------- CSR build: histogram -> shfl scan -> scatter (once per launch)
__global__ void k_hist(const int* __restrict__ rows, int* __restrict__ cnt) {
    int e = blockIdx.x * blockDim.x + threadIdx.x;
    if (e < NNZS) atomicAdd(&cnt[rows[e]], 1);
}

__global__ __launch_bounds__(1024) void k_scan(const int* __restrict__ cnt,
                                               int* __restrict__ rp, int* __restrict__ wp) {
    __shared__ int wsum[16];
    __shared__ int carry;
    int tid = threadIdx.x, lane = tid & 63, wid = tid >> 6;
    if (tid == 0) { carry = 0; rp[0] = 0; }
    __syncthreads();
    for (int base = 0; base < NN; base += 1024) {
        int i = base + tid;
        int v = (i < NN) ? cnt[i] : 0;
        int x = v;
#pragma unroll
        for (int off = 1; off < 64; off <<= 1) {
            int t = __shfl_up(x, off, 64);
            if (lane >= off) x += t;
        }
        if (lane == 63) wsum[wid] = x;
        __syncthreads();
        if (tid < 16) {
            int y = wsum[tid];
#pragma unroll
            for (int off = 1; off < 16; off <<= 1) {
                int t = __shfl_up(y, off, 64);
                if (tid >= off) y += t;
            }
            wsum[tid] = y;
        }
        __syncthreads();
        int blockoff = (wid == 0) ? 0 : wsum[wid - 1];
        int c = carry;
        int incl = c + blockoff + x;
        if (i < NN) { rp[i + 1] = incl; wp[i] = incl - v; }
        int total = wsum[15];
        __syncthreads();
        if (tid == 0) carry = c + total;
        __syncthreads();
    }
}

__global__ void k_scatter(const int* __restrict__ rows, const int* __restrict__ cols,
                          const float* __restrict__ vals, int* __restrict__ wp,
                          int2* __restrict__ edat) {
    int e = blockIdx.x * blockDim.x + threadIdx.x;
    if (e >= NNZS) return;
    int r = rows[e];
    int pos = atomicAdd(&wp[r], 1);
    edat[pos] = make_int2(cols[e], __float_as_int(vals[e]));
}

// ---------------- side[r] = sum_e val_e * ego[col_e]: one wave per row, lane = dim, no atomics
__global__ void k_spmm_csr(const int* __restrict__ rp, const int2* __restrict__ edat,
                           const float* __restrict__ ego, float* __restrict__ side) {
    int lane = threadIdx.x & 63;
    int wave = (blockIdx.x * blockDim.x + threadIdx.x) >> 6;
    int nw   = (gridDim.x * blockDim.x) >> 6;
    for (int r = wave; r < NN; r += nw) {
        int e0 = rp[r], e1 = rp[r + 1];
        float acc = 0.f;
        int e = e0;
        for (; e + 8 <= e1; e += 8) {
            int2 d[8];
#pragma unroll
            for (int j = 0; j < 8; ++j) d[j] = edat[e + j];
#pragma unroll
            for (int j = 0; j < 8; ++j)
                acc = fmaf(__int_as_float(d[j].y), ego[(size_t)d[j].x * DD + lane], acc);
        }
        for (; e < e1; ++e) {
            int2 d = edat[e];
            acc = fmaf(__int_as_float(d.y), ego[(size_t)d.x * DD + lane], acc);
        }
        side[(size_t)r * DD + lane] = acc;
    }
}

// ---------------- ego = leaky(side@gcW^T+gcb) + leaky((ego*side)@biW^T+bib); bf16 copy to all_emb cols
__global__ __launch_bounds__(256) void k_dense(const float* __restrict__ side, float* __restrict__ ego,
                        const float* __restrict__ gcW, const float* __restrict__ gcb,
                        const float* __restrict__ biW, const float* __restrict__ bib,
                        unsigned short* __restrict__ allemb, int colofs) {
    __shared__ float wg[DD * DD];   // transposed: wg[k][o]
    __shared__ float wb[DD * DD];
    int tid = threadIdx.x;
    for (int i = tid; i < DD * DD; i += blockDim.x) {
        int o = i >> 6, k = i & 63;
        wg[k * DD + o] = gcW[i];
        wb[k * DD + o] = biW[i];
    }
    __syncthreads();
    int lane = tid & 63;
    int wave = (blockIdx.x * blockDim.x + tid) >> 6;
    int nw   = (gridDim.x * blockDim.x) >> 6;
    float bg = gcb[lane], bb = bib[lane];
    for (int n = wave; n < NN; n += nw) {
        float s = side[(size_t)n * DD + lane];
        float e = ego[(size_t)n * DD + lane];
        float p = e * s;
        float a1 = bg, a2 = bb;
#pragma unroll
        for (int k = 0; k < DD; ++k) {
            float sk = __shfl(s, k, 64);
            float pk = __shfl(p, k, 64);
            a1 = fmaf(sk, wg[k * DD + lane], a1);
            a2 = fmaf(pk, wb[k * DD + lane], a2);
        }
        a1 = a1 > 0.f ? a1 : 0.01f * a1;
        a2 = a2 > 0.f ? a2 : 0.01f * a2;
        float o = a1 + a2;
        ego[(size_t)n * DD + lane] = o;
        allemb[(size_t)n * KD + colofs + lane] = f2bf(o);
    }
}

// ---------------- kernel A: per-row online (max, sum-exp) partials over a 640-col chunk
// 1-D grid RBLK*NCH, chunk-major (consecutive blocks share the B chunk -> L2-resident).
// block 256 = 4 waves x 32 rows = 128 rows; lane-local online state, merge once at end.
__global__ __launch_bounds__(256) void k_lse_part(const unsigned short* __restrict__ allemb,
                                                  float* __restrict__ pm, float* __restrict__ ps) {
    int id = blockIdx.x;
    int rowblk = id % RBLK;
    int chunk  = id / RBLK;
    int lane = threadIdx.x & 63;
    int wave = threadIdx.x >> 6;
    int r0 = rowblk * 128 + wave * 32;
    int c0 = chunk * ACHUNK;
    const unsigned short* A = allemb;                       // user rows
    const unsigned short* B = allemb + (size_t)NU * KD;     // item rows
    int kofs = (lane >> 4) * 8;

    short8 a[2][6];
#pragma unroll
    for (int mi = 0; mi < 2; ++mi) {
        int ar = r0 + mi * 16 + (lane & 15);
        if (ar >= NU) ar = NU - 1;      // ragged row guard
#pragma unroll
        for (int kt = 0; kt < 6; ++kt)
            a[mi][kt] = *(const short8*)(A + (size_t)ar * KD + kt * 32 + kofs);
    }

    float m[2][4], s[2][4];
#pragma unroll
    for (int mi = 0; mi < 2; ++mi)
#pragma unroll
        for (int r = 0; r < 4; ++r) { m[mi][r] = -INFINITY; s[mi][r] = 0.f; }

    for (int t = 0; t < CTILES; ++t) {
        int c = c0 + t * 128;
        f32x4 acc[2][8];
#pragma unroll
        for (int mi = 0; mi < 2; ++mi)
#pragma unroll
            for (int nf = 0; nf < 8; ++nf) acc[mi][nf] = (f32x4){0.f, 0.f, 0.f, 0.f};
#pragma unroll
        for (int nf = 0; nf < 8; ++nf) {
            const unsigned short* bp = B + (size_t)(c + nf * 16 + (lane & 15)) * KD + kofs;
#pragma unroll
            for (int kt = 0; kt < 6; ++kt) {
                short8 b = *(const short8*)(bp + kt * 32);
                acc[0][nf] = __builtin_amdgcn_mfma_f32_16x16x32_bf16(a[0][kt], b, acc[0][nf], 0, 0, 0);
                acc[1][nf] = __builtin_amdgcn_mfma_f32_16x16x32_bf16(a[1][kt], b, acc[1][nf], 0, 0, 0);
            }
        }
#pragma unroll
        for (int mi = 0; mi < 2; ++mi)
#pragma unroll
            for (int r = 0; r < 4; ++r) {
                float lm = acc[mi][0][r];
#pragma unroll
                for (int nf = 1; nf < 8; ++nf) lm = fmaxf(lm, acc[mi][nf][r]);
                float nm = fmaxf(m[mi][r], lm);
                float p = 0.f;
#pragma unroll
                for (int nf = 0; nf < 8; ++nf) p += __expf(acc[mi][nf][r] - nm);
                s[mi][r] = s[mi][r] * __expf(m[mi][r] - nm) + p;
                m[mi][r] = nm;
            }
    }
#pragma unroll
    for (int mi = 0; mi < 2; ++mi)
#pragma unroll
        for (int r = 0; r < 4; ++r) {
            float mm = m[mi][r], ss = s[mi][r];
#pragma unroll
            for (int off = 1; off < 16; off <<= 1) {
                float om = __shfl_xor(mm, off, 64);
                float os = __shfl_xor(ss, off, 64);
                float nm = fmaxf(mm, om);
                ss = ss * __expf(mm - nm) + os * __expf(om - nm);
                mm = nm;
            }
            m[mi][r] = mm; s[mi][r] = ss;
        }
    if ((lane & 15) == 0) {
        int g = lane >> 4;
#pragma unroll
        for (int mi = 0; mi < 2; ++mi)
#pragma unroll
            for (int r = 0; r < 4; ++r) {
                int row = r0 + mi * 16 + g * 4 + r;
                if (row < NU) {
                    pm[chunk * NU + row] = m[mi][r];
                    ps[chunk * NU + row] = s[mi][r];
                }
            }
    }
}

// ---------------- combine partials: lse[r] = m + log(sum)
__global__ void k_lse_comb(const float* __restrict__ pm, const float* __restrict__ ps,
                           float* __restrict__ lse) {
    int r = blockIdx.x * blockDim.x + threadIdx.x;
    if (r >= NU) return;
    float m = -INFINITY;
    for (int c = 0; c < NCH; ++c) m = fmaxf(m, pm[c * NU + r]);
    float s = 0.f;
    for (int c = 0; c < NCH; ++c) s += ps[c * NU + r] * __expf(pm[c * NU + r] - m);
    lse[r] = m + __logf(s);
}

// ---------------- kernel B: recompute scores, write out = s - lse[row]
// 1-D grid RBLK*125, colblk-major (consecutive blocks share the 49 KB B tile -> L2).
// block 256 = 4 waves; tile 128 x 128; LDS-staged coalesced float4 stores.
__global__ __launch_bounds__(256) void k_out(const unsigned short* __restrict__ allemb,
                                             const float* __restrict__ lse, float* __restrict__ out) {
    __shared__ float tile[4][16][132];
    int id = blockIdx.x;
    int rowblk = id % RBLK;
    int colblk = id / RBLK;
    int lane = threadIdx.x & 63;
    int wave = threadIdx.x >> 6;
    int r0 = rowblk * 128 + wave * 32;
    int c0 = colblk * 128;
    const unsigned short* A = allemb;
    const unsigned short* B = allemb + (size_t)NU * KD;
    int kofs = (lane >> 4) * 8;
    int g = lane >> 4;

    short8 a[2][6];
#pragma unroll
    for (int mi = 0; mi < 2; ++mi) {
        int ar = r0 + mi * 16 + (lane & 15);
        if (ar >= NU) ar = NU - 1;   // ragged row guard
#pragma unroll
        for (int kt = 0; kt < 6; ++kt)
            a[mi][kt] = *(const short8*)(A + (size_t)ar * KD + kt * 32 + kofs);
    }

    f32x4 acc[2][8];
#pragma unroll
    for (int mi = 0; mi < 2; ++mi)
#pragma unroll
        for (int nf = 0; nf < 8; ++nf) acc[mi][nf] = (f32x4){0.f, 0.f, 0.f, 0.f};
#pragma unroll
    for (int nf = 0; nf < 8; ++nf) {
        const unsigned short* bp = B + (size_t)(c0 + nf * 16 + (lane & 15)) * KD + kofs;
#pragma unroll
        for (int kt = 0; kt < 6; ++kt) {
            short8 b = *(const short8*)(bp + kt * 32);
            acc[0][nf] = __builtin_amdgcn_mfma_f32_16x16x32_bf16(a[0][kt], b, acc[0][nf], 0, 0, 0);
            acc[1][nf] = __builtin_amdgcn_mfma_f32_16x16x32_bf16(a[1][kt], b, acc[1][nf], 0, 0, 0);
        }
    }

    float l4[2][4];
#pragma unroll
    for (int mi = 0; mi < 2; ++mi)
#pragma unroll
        for (int r = 0; r < 4; ++r) {
            int row = r0 + mi * 16 + g * 4 + r;
            l4[mi][r] = lse[row >= NU ? NU - 1 : row];
        }

#pragma unroll
    for (int mi = 0; mi < 2; ++mi) {
        int rowbase = r0 + mi * 16;
#pragma unroll
        for (int nf = 0; nf < 8; ++nf)
#pragma unroll
            for (int r = 0; r < 4; ++r)
                tile[wave][g * 4 + r][nf * 16 + (lane & 15)] = acc[mi][nf][r] - l4[mi][r];
#pragma unroll
        for (int it = 0; it < 8; ++it) {
            int idx = it * 64 + lane;
            int rr = idx >> 5;
            int cc = (idx & 31) * 4;
            int row = rowbase + rr;
            if (row < NU) {
                f32x4 v = *(const f32x4*)&tile[wave][rr][cc];
                *(f32x4*)&out[(size_t)row * NI + c0 + cc] = v;
            }
        }
    }
}

extern "C" void kernel_launch(void* const* d_in, const int* in_sizes, int n_in,
                              void* d_out, int out_size, void* d_ws, size_t ws_size,
                              hipStream_t stream) {
    const int*   uidx = (const int*)d_in[0];
    const int*   iidx = (const int*)d_in[1];
    const int*   arow = (const int*)d_in[2];
    const int*   acol = (const int*)d_in[3];
    const float* aval = (const float*)d_in[4];
    const float* ue   = (const float*)d_in[5];
    const float* ie   = (const float*)d_in[6];
    const float* gcW  = (const float*)d_in[7];
    const float* gcb  = (const float*)d_in[8];
    const float* biW  = (const float*)d_in[9];
    const float* bib  = (const float*)d_in[10];
    float* out = (float*)d_out;

    char* w = (char*)d_ws;
    float* ego  = (float*)w;                      w += (size_t)NN * DD * sizeof(float);
    float* side = (float*)w;                      w += (size_t)NN * DD * sizeof(float);
    unsigned short* allemb = (unsigned short*)w;  w += (size_t)NN * KD * sizeof(unsigned short);
    float* pm  = (float*)w;                       w += (size_t)NCH * NU * sizeof(float);
    float* ps  = (float*)w;                       w += (size_t)NCH * NU * sizeof(float);
    float* lse = (float*)w;                       w += (size_t)NU * sizeof(float);
    int* cnt   = (int*)w;                         w += (size_t)NN * sizeof(int);
    int* rp    = (int*)w;                         w += (size_t)(NN + 2) * sizeof(int);  // +2 keeps edat 8B-aligned
    int* wp    = (int*)w;                         w += (size_t)NN * sizeof(int);
    int2* edat = (int2*)w;                        w += (size_t)NNZS * sizeof(int2);

    k_concat<<<(NN * DD + 255) / 256, 256, 0, stream>>>(uidx, iidx, ue, ie, ego, allemb);

    // CSR build (shared by both layers)
    hipMemsetAsync(cnt, 0, (size_t)NN * sizeof(int), stream);
    k_hist<<<(NNZS + 255) / 256, 256, 0, stream>>>(arow, cnt);
    k_scan<<<1, 1024, 0, stream>>>(cnt, rp, wp);
    k_scatter<<<(NNZS + 255) / 256, 256, 0, stream>>>(arow, acol, aval, wp, edat);

    for (int l = 0; l < NL; ++l) {
        k_spmm_csr<<<3000, 256, 0, stream>>>(rp, edat, ego, side);
        k_dense<<<512, 256, 0, stream>>>(side, ego, gcW + l * DD * DD, gcb + l * DD,
                                         biW + l * DD * DD, bib + l * DD, allemb, (l + 1) * DD);
    }

    k_lse_part<<<RBLK * NCH, 256, 0, stream>>>(allemb, pm, ps);
    k_lse_comb<<<(NU + 255) / 256, 256, 0, stream>>>(pm, ps, lse);
    k_out<<<RBLK * 125, 256, 0, stream>>>(allemb, lse, out);
}

// Round 5
// 692.123 us; speedup vs baseline: 1.5029x; 1.0870x over previous
//
#include <hip/hip_runtime.h>
#include <hip/hip_bf16.h>
#include <math.h>

#define NU   8000
#define NI   16000
#define NN   24000
#define DD   64
#define NL   2
#define NNZS 768000
#define KD   192        // 3 * 64 concat width
#define NCH  25         // column chunks for lse partials
#define ACHUNK 640      // 16000 / NCH
#define CTILES 5        // ACHUNK / 128
#define RBLK 63         // ceil(8000/128) row blocks for both GEMMs

typedef __attribute__((ext_vector_type(8))) short  short8;
typedef __attribute__((ext_vector_type(4))) float  f32x4;

__device__ __forceinline__ unsigned short f2bf(float x) {
    union { float f; unsigned int u; } v; v.f = x;
    unsigned int r = v.u + 0x7fff + ((v.u >> 16) & 1);   // round-nearest-even
    return (unsigned short)(r >> 16);
}

// ---------------- ego = concat(user_emb, item_emb); bf16 copy into all_emb[:, 0:64];
// also zero the CSR histogram and convert both W stacks to bf16 (one dispatch)
__global__ void k_concat(const int* __restrict__ uidx, const int* __restrict__ iidx,
                         const float* __restrict__ ue, const float* __restrict__ ie,
                         const float* __restrict__ gcW, const float* __restrict__ biW,
                         float* __restrict__ ego, unsigned short* __restrict__ allemb,
                         unsigned short* __restrict__ wbf, int* __restrict__ cnt) {
    int t = blockIdx.x * blockDim.x + threadIdx.x;
    if (t < NN) cnt[t] = 0;
    if (t < NL * DD * DD) {
        wbf[t] = f2bf(gcW[t]);                       // gc W bf16
        wbf[NL * DD * DD + t] = f2bf(biW[t]);        // bi W bf16
    }
    if (t >= NN * DD) return;
    int n = t >> 6, d = t & 63;
    float v = (n < NU) ? ue[uidx[n] * DD + d] : ie[iidx[n - NU] * DD + d];
    ego[t] = v;
    allemb[(size_t)n * KD + d] = f2bf(v);
}

// ---------------- CSR build: histogram -> shfl scan -> scatter (once per launch)
__global__ void k_hist(const int* __restrict__ rows, int* __restrict__ cnt) {
    int e = blockIdx.x * blockDim.x + threadIdx.x;
    if (e < NNZS) atomicAdd(&cnt[rows[e]], 1);
}

__global__ __launch_bounds__(1024) void k_scan(const int* __restrict__ cnt,
                                               int* __restrict__ rp, int* __restrict__ wp) {
    __shared__ int wsum[16];
    __shared__ int carry;
    int tid = threadIdx.x, lane = tid & 63, wid = tid >> 6;
    if (tid == 0) { carry = 0; rp[0] = 0; }
    __syncthreads();
    for (int base = 0; base < NN; base += 1024) {
        int i = base + tid;
        int v = (i < NN) ? cnt[i] : 0;
        int x = v;
#pragma unroll
        for (int off = 1; off < 64; off <<= 1) {
            int t = __shfl_up(x, off, 64);
            if (lane >= off) x += t;
        }
        if (lane == 63) wsum[wid] = x;
        __syncthreads();
        if (tid < 16) {
            int y = wsum[tid];
#pragma unroll
            for (int off = 1; off < 16; off <<= 1) {
                int t = __shfl_up(y, off, 64);
                if (tid >= off) y += t;
            }
            wsum[tid] = y;
        }
        __syncthreads();
        int blockoff = (wid == 0) ? 0 : wsum[wid - 1];
        int c = carry;
        int incl = c + blockoff + x;
        if (i < NN) { rp[i + 1] = incl; wp[i] = incl - v; }
        int total = wsum[15];
        __syncthreads();
        if (tid == 0) carry = c + total;
        __syncthreads();
    }
}

__global__ void k_scatter(const int* __restrict__ rows, const int* __restrict__ cols,
                          const float* __restrict__ vals, int* __restrict__ wp,
                          int2* __restrict__ edat) {
    int e = blockIdx.x * blockDim.x + threadIdx.x;
    if (e >= NNZS) return;
    int r = rows[e];
    int pos = atomicAdd(&wp[r], 1);
    edat[pos] = make_int2(cols[e], __float_as_int(vals[e]));
}

// ---------------- side[r] = sum_e val_e * ego[col_e]: one wave per row, lane = dim, no atomics
__global__ void k_spmm_csr(const int* __restrict__ rp, const int2* __restrict__ edat,
                           const float* __restrict__ ego, float* __restrict__ side) {
    int lane = threadIdx.x & 63;
    int wave = (blockIdx.x * blockDim.x + threadIdx.x) >> 6;
    int nw   = (gridDim.x * blockDim.x) >> 6;
    for (int r = wave; r < NN; r += nw) {
        int e0 = rp[r], e1 = rp[r + 1];
        float acc = 0.f;
        int e = e0;
        for (; e + 8 <= e1; e += 8) {
            int2 d[8];
#pragma unroll
            for (int j = 0; j < 8; ++j) d[j] = edat[e + j];
#pragma unroll
            for (int j = 0; j < 8; ++j)
                acc = fmaf(__int_as_float(d[j].y), ego[(size_t)d[j].x * DD + lane], acc);
        }
        for (; e < e1; ++e) {
            int2 d = edat[e];
            acc = fmaf(__int_as_float(d.y), ego[(size_t)d.x * DD + lane], acc);
        }
        side[(size_t)r * DD + lane] = acc;
    }
}

// ---------------- dense layer via MFMA: ego = leaky(side@WgT+bg) + leaky((ego*side)@WbT+bb)
// block 256 = 4 waves, each wave 16 nodes x 64 outputs; grid 375 (= 24000/64)
// Same self-consistent fragment formulas as the big GEMMs.
__global__ __launch_bounds__(256) void k_dense(const float* __restrict__ side, float* __restrict__ ego,
                        const unsigned short* __restrict__ wg_bf,
                        const unsigned short* __restrict__ wb_bf,
                        const float* __restrict__ gcb, const float* __restrict__ bib,
                        unsigned short* __restrict__ allemb, int colofs) {
    int lane = threadIdx.x & 63;
    int wave = threadIdx.x >> 6;
    int n0 = (blockIdx.x * 4 + wave) * 16;
    int nrow = lane & 15;
    int kofs = (lane >> 4) * 8;

    // B fragments: W rows are the N dim (output features o), k = columns
    short8 bg[4][2], bb[4][2];
#pragma unroll
    for (int nf = 0; nf < 4; ++nf)
#pragma unroll
        for (int kt = 0; kt < 2; ++kt) {
            bg[nf][kt] = *(const short8*)(wg_bf + (nf * 16 + nrow) * DD + kt * 32 + kofs);
            bb[nf][kt] = *(const short8*)(wb_bf + (nf * 16 + nrow) * DD + kt * 32 + kofs);
        }

    // A fragments: side row (gc path), ego*side row (bi path), converted to bf16
    short8 a1[2], a2[2];
    const float* sp = side + (size_t)(n0 + nrow) * DD;
    const float* ep = ego  + (size_t)(n0 + nrow) * DD;
#pragma unroll
    for (int kt = 0; kt < 2; ++kt) {
        int o = kt * 32 + kofs;
#pragma unroll
        for (int j = 0; j < 8; ++j) {
            float s = sp[o + j];
            float e = ep[o + j];
            a1[kt][j] = (short)f2bf(s);
            a2[kt][j] = (short)f2bf(e * s);
        }
    }

    f32x4 acc1[4], acc2[4];
#pragma unroll
    for (int nf = 0; nf < 4; ++nf) { acc1[nf] = (f32x4){0,0,0,0}; acc2[nf] = (f32x4){0,0,0,0}; }
#pragma unroll
    for (int nf = 0; nf < 4; ++nf)
#pragma unroll
        for (int kt = 0; kt < 2; ++kt) {
            acc1[nf] = __builtin_amdgcn_mfma_f32_16x16x32_bf16(a1[kt], bg[nf][kt], acc1[nf], 0, 0, 0);
            acc2[nf] = __builtin_amdgcn_mfma_f32_16x16x32_bf16(a2[kt], bb[nf][kt], acc2[nf], 0, 0, 0);
        }

    int g = lane >> 4;
#pragma unroll
    for (int nf = 0; nf < 4; ++nf) {
        int o = nf * 16 + nrow;
        float b1 = gcb[o], b2 = bib[o];
#pragma unroll
        for (int r = 0; r < 4; ++r) {
            int node = n0 + g * 4 + r;
            float v1 = acc1[nf][r] + b1;
            float v2 = acc2[nf][r] + b2;
            v1 = v1 > 0.f ? v1 : 0.01f * v1;
            v2 = v2 > 0.f ? v2 : 0.01f * v2;
            float v = v1 + v2;
            ego[(size_t)node * DD + o] = v;
            allemb[(size_t)node * KD + colofs + o] = f2bf(v);
        }
    }
}

// ---------------- kernel A: per-row online (max, sum-exp) partials over a 640-col chunk
// 1-D grid RBLK*NCH, chunk-major; block 256 = 4 waves x 32 rows; lane-local online state.
__global__ __launch_bounds__(256) void k_lse_part(const unsigned short* __restrict__ allemb,
                                                  float* __restrict__ pm, float* __restrict__ ps) {
    int id = blockIdx.x;
    int rowblk = id % RBLK;
    int chunk  = id / RBLK;
    int lane = threadIdx.x & 63;
    int wave = threadIdx.x >> 6;
    int r0 = rowblk * 128 + wave * 32;
    int c0 = chunk * ACHUNK;
    const unsigned short* A = allemb;
    const unsigned short* B = allemb + (size_t)NU * KD;
    int kofs = (lane >> 4) * 8;

    short8 a[2][6];
#pragma unroll
    for (int mi = 0; mi < 2; ++mi) {
        int ar = r0 + mi * 16 + (lane & 15);
        if (ar >= NU) ar = NU - 1;
#pragma unroll
        for (int kt = 0; kt < 6; ++kt)
            a[mi][kt] = *(const short8*)(A + (size_t)ar * KD + kt * 32 + kofs);
    }

    float m[2][4], s[2][4];
#pragma unroll
    for (int mi = 0; mi < 2; ++mi)
#pragma unroll
        for (int r = 0; r < 4; ++r) { m[mi][r] = -INFINITY; s[mi][r] = 0.f; }

    for (int t = 0; t < CTILES; ++t) {
        int c = c0 + t * 128;
        f32x4 acc[2][8];
#pragma unroll
        for (int mi = 0; mi < 2; ++mi)
#pragma unroll
            for (int nf = 0; nf < 8; ++nf) acc[mi][nf] = (f32x4){0.f, 0.f, 0.f, 0.f};
#pragma unroll
        for (int nf = 0; nf < 8; ++nf) {
            const unsigned short* bp = B + (size_t)(c + nf * 16 + (lane & 15)) * KD + kofs;
#pragma unroll
            for (int kt = 0; kt < 6; ++kt) {
                short8 b = *(const short8*)(bp + kt * 32);
                acc[0][nf] = __builtin_amdgcn_mfma_f32_16x16x32_bf16(a[0][kt], b, acc[0][nf], 0, 0, 0);
                acc[1][nf] = __builtin_amdgcn_mfma_f32_16x16x32_bf16(a[1][kt], b, acc[1][nf], 0, 0, 0);
            }
        }
#pragma unroll
        for (int mi = 0; mi < 2; ++mi)
#pragma unroll
            for (int r = 0; r < 4; ++r) {
                float lm = acc[mi][0][r];
#pragma unroll
                for (int nf = 1; nf < 8; ++nf) lm = fmaxf(lm, acc[mi][nf][r]);
                float nm = fmaxf(m[mi][r], lm);
                float p = 0.f;
#pragma unroll
                for (int nf = 0; nf < 8; ++nf) p += __expf(acc[mi][nf][r] - nm);
                s[mi][r] = s[mi][r] * __expf(m[mi][r] - nm) + p;
                m[mi][r] = nm;
            }
    }
#pragma unroll
    for (int mi = 0; mi < 2; ++mi)
#pragma unroll
        for (int r = 0; r < 4; ++r) {
            float mm = m[mi][r], ss = s[mi][r];
#pragma unroll
            for (int off = 1; off < 16; off <<= 1) {
                float om = __shfl_xor(mm, off, 64);
                float os = __shfl_xor(ss, off, 64);
                float nm = fmaxf(mm, om);
                ss = ss * __expf(mm - nm) + os * __expf(om - nm);
                mm = nm;
            }
            m[mi][r] = mm; s[mi][r] = ss;
        }
    if ((lane & 15) == 0) {
        int g = lane >> 4;
#pragma unroll
        for (int mi = 0; mi < 2; ++mi)
#pragma unroll
            for (int r = 0; r < 4; ++r) {
                int row = r0 + mi * 16 + g * 4 + r;
                if (row < NU) {
                    pm[chunk * NU + row] = m[mi][r];
                    ps[chunk * NU + row] = s[mi][r];
                }
            }
    }
}

// ---------------- kernel B: recompute scores, write out = s - lse[row]; lse fused from pm/ps
__global__ __launch_bounds__(256) void k_out(const unsigned short* __restrict__ allemb,
                                             const float* __restrict__ pm, const float* __restrict__ ps,
                                             float* __restrict__ out) {
    __shared__ float lse_s[128];
    __shared__ float tile[4][16][132];
    int id = blockIdx.x;
    int rowblk = id % RBLK;
    int colblk = id / RBLK;
    int tid = threadIdx.x;

    // fused lse for this block's 128 rows
    if (tid < 128) {
        int row = rowblk * 128 + tid;
        if (row >= NU) row = NU - 1;
        float mm = -INFINITY;
#pragma unroll
        for (int c = 0; c < NCH; ++c) mm = fmaxf(mm, pm[c * NU + row]);
        float ss = 0.f;
#pragma unroll
        for (int c = 0; c < NCH; ++c) ss += ps[c * NU + row] * __expf(pm[c * NU + row] - mm);
        lse_s[tid] = mm + __logf(ss);
    }
    __syncthreads();

    int lane = tid & 63;
    int wave = tid >> 6;
    int r0 = rowblk * 128 + wave * 32;
    int c0 = colblk * 128;
    const unsigned short* A = allemb;
    const unsigned short* B = allemb + (size_t)NU * KD;
    int kofs = (lane >> 4) * 8;
    int g = lane >> 4;

    short8 a[2][6];
#pragma unroll
    for (int mi = 0; mi < 2; ++mi) {
        int ar = r0 + mi * 16 + (lane & 15);
        if (ar >= NU) ar = NU - 1;
#pragma unroll
        for (int kt = 0; kt < 6; ++kt)
            a[mi][kt] = *(const short8*)(A + (size_t)ar * KD + kt * 32 + kofs);
    }

    f32x4 acc[2][8];
#pragma unroll
    for (int mi = 0; mi < 2; ++mi)
#pragma unroll
        for (int nf = 0; nf < 8; ++nf) acc[mi][nf] = (f32x4){0.f, 0.f, 0.f, 0.f};
#pragma unroll
    for (int nf = 0; nf < 8; ++nf) {
        const unsigned short* bp = B + (size_t)(c0 + nf * 16 + (lane & 15)) * KD + kofs;
#pragma unroll
        for (int kt = 0; kt < 6; ++kt) {
            short8 b = *(const short8*)(bp + kt * 32);
            acc[0][nf] = __builtin_amdgcn_mfma_f32_16x16x32_bf16(a[0][kt], b, acc[0][nf], 0, 0, 0);
            acc[1][nf] = __builtin_amdgcn_mfma_f32_16x16x32_bf16(a[1][kt], b, acc[1][nf], 0, 0, 0);
        }
    }

    float l4[2][4];
#pragma unroll
    for (int mi = 0; mi < 2; ++mi)
#pragma unroll
        for (int r = 0; r < 4; ++r)
            l4[mi][r] = lse_s[wave * 32 + mi * 16 + g * 4 + r];

#pragma unroll
    for (int mi = 0; mi < 2; ++mi) {
        int rowbase = r0 + mi * 16;
#pragma unroll
        for (int nf = 0; nf < 8; ++nf)
#pragma unroll
            for (int r = 0; r < 4; ++r)
                tile[wave][g * 4 + r][nf * 16 + (lane & 15)] = acc[mi][nf][r] - l4[mi][r];
#pragma unroll
        for (int it = 0; it < 8; ++it) {
            int idx = it * 64 + lane;
            int rr = idx >> 5;
            int cc = (idx & 31) * 4;
            int row = rowbase + rr;
            if (row < NU) {
                f32x4 v = *(const f32x4*)&tile[wave][rr][cc];
                *(f32x4*)&out[(size_t)row * NI + c0 + cc] = v;
            }
        }
    }
}

extern "C" void kernel_launch(void* const* d_in, const int* in_sizes, int n_in,
                              void* d_out, int out_size, void* d_ws, size_t ws_size,
                              hipStream_t stream) {
    const int*   uidx = (const int*)d_in[0];
    const int*   iidx = (const int*)d_in[1];
    const int*   arow = (const int*)d_in[2];
    const int*   acol = (const int*)d_in[3];
    const float* aval = (const float*)d_in[4];
    const float* ue   = (const float*)d_in[5];
    const float* ie   = (const float*)d_in[6];
    const float* gcW  = (const float*)d_in[7];
    const float* gcb  = (const float*)d_in[8];
    const float* biW  = (const float*)d_in[9];
    const float* bib  = (const float*)d_in[10];
    float* out = (float*)d_out;

    char* w = (char*)d_ws;
    float* ego  = (float*)w;                      w += (size_t)NN * DD * sizeof(float);
    float* side = (float*)w;                      w += (size_t)NN * DD * sizeof(float);
    unsigned short* allemb = (unsigned short*)w;  w += (size_t)NN * KD * sizeof(unsigned short);
    float* pm  = (float*)w;                       w += (size_t)NCH * NU * sizeof(float);
    float* ps  = (float*)w;                       w += (size_t)NCH * NU * sizeof(float);
    unsigned short* wbf = (unsigned short*)w;     w += (size_t)2 * NL * DD * DD * sizeof(unsigned short);
    int* cnt   = (int*)w;                         w += (size_t)NN * sizeof(int);
    int* rp    = (int*)w;                         w += (size_t)(NN + 2) * sizeof(int);  // +2 keeps edat 8B-aligned
    int* wp    = (int*)w;                         w += (size_t)NN * sizeof(int);
    int2* edat = (int2*)w;                        w += (size_t)NNZS * sizeof(int2);

    unsigned short* wg_bf = wbf;                  // [NL][64][64]
    unsigned short* wb_bf = wbf + NL * DD * DD;

    k_concat<<<(NN * DD + 255) / 256, 256, 0, stream>>>(uidx, iidx, ue, ie, gcW, biW,
                                                        ego, allemb, wbf, cnt);

    // CSR build (shared by both layers)
    k_hist<<<(NNZS + 255) / 256, 256, 0, stream>>>(arow, cnt);
    k_scan<<<1, 1024, 0, stream>>>(cnt, rp, wp);
    k_scatter<<<(NNZS + 255) / 256, 256, 0, stream>>>(arow, acol, aval, wp, edat);

    for (int l = 0; l < NL; ++l) {
        k_spmm_csr<<<3000, 256, 0, stream>>>(rp, edat, ego, side);
        k_dense<<<NN / 64, 256, 0, stream>>>(side, ego, wg_bf + l * DD * DD, wb_bf + l * DD * DD,
                                             gcb + l * DD, bib + l * DD, allemb, (l + 1) * DD);
    }

    k_lse_part<<<RBLK * NCH, 256, 0, stream>>>(allemb, pm, ps);
    k_out<<<RBLK * 125, 256, 0, stream>>>(allemb, pm, ps, out);
}

// Round 6
// 659.123 us; speedup vs baseline: 1.5781x; 1.0501x over previous
//
#include <hip/hip_runtime.h>
#include <hip/hip_bf16.h>
#include <math.h>

#define NU   8000
#define NI   16000
#define NN   24000
#define DD   64
#define NL   2
#define NNZS 768000
#define KD   192        // 3 * 64 concat width
#define NCH  25         // column chunks for lse partials
#define ACHUNK 640      // 16000 / NCH
#define CTILES 5        // ACHUNK / 128
#define RBLK 63         // ceil(8000/128) row blocks for both GEMMs
#define CBLK 125        // 16000 / 128 col blocks for k_out

typedef __attribute__((ext_vector_type(8))) short  short8;
typedef __attribute__((ext_vector_type(4))) float  f32x4;

__device__ __forceinline__ unsigned short f2bf(float x) {
    union { float f; unsigned int u; } v; v.f = x;
    unsigned int r = v.u + 0x7fff + ((v.u >> 16) & 1);   // round-nearest-even
    return (unsigned short)(r >> 16);
}

// ---------------- ego = concat(user_emb, item_emb); bf16 copy into all_emb[:, 0:64];
// also zero the CSR histogram and convert both W stacks to bf16 (one dispatch)
__global__ void k_concat(const int* __restrict__ uidx, const int* __restrict__ iidx,
                         const float* __restrict__ ue, const float* __restrict__ ie,
                         const float* __restrict__ gcW, const float* __restrict__ biW,
                         float* __restrict__ ego, unsigned short* __restrict__ allemb,
                         unsigned short* __restrict__ wbf, int* __restrict__ cnt) {
    int t = blockIdx.x * blockDim.x + threadIdx.x;
    if (t < NN) cnt[t] = 0;
    if (t < NL * DD * DD) {
        wbf[t] = f2bf(gcW[t]);                       // gc W bf16
        wbf[NL * DD * DD + t] = f2bf(biW[t]);        // bi W bf16
    }
    if (t >= NN * DD) return;
    int n = t >> 6, d = t & 63;
    float v = (n < NU) ? ue[uidx[n] * DD + d] : ie[iidx[n - NU] * DD + d];
    ego[t] = v;
    allemb[(size_t)n * KD + d] = f2bf(v);
}

// ---------------- CSR build: histogram -> shfl scan -> scatter (once per launch)
__global__ void k_hist(const int* __restrict__ rows, int* __restrict__ cnt) {
    int e = blockIdx.x * blockDim.x + threadIdx.x;
    if (e < NNZS) atomicAdd(&cnt[rows[e]], 1);
}

__global__ __launch_bounds__(1024) void k_scan(const int* __restrict__ cnt,
                                               int* __restrict__ rp, int* __restrict__ wp) {
    __shared__ int wsum[16];
    __shared__ int carry;
    int tid = threadIdx.x, lane = tid & 63, wid = tid >> 6;
    if (tid == 0) { carry = 0; rp[0] = 0; }
    __syncthreads();
    for (int base = 0; base < NN; base += 1024) {
        int i = base + tid;
        int v = (i < NN) ? cnt[i] : 0;
        int x = v;
#pragma unroll
        for (int off = 1; off < 64; off <<= 1) {
            int t = __shfl_up(x, off, 64);
            if (lane >= off) x += t;
        }
        if (lane == 63) wsum[wid] = x;
        __syncthreads();
        if (tid < 16) {
            int y = wsum[tid];
#pragma unroll
            for (int off = 1; off < 16; off <<= 1) {
                int t = __shfl_up(y, off, 64);
                if (tid >= off) y += t;
            }
            wsum[tid] = y;
        }
        __syncthreads();
        int blockoff = (wid == 0) ? 0 : wsum[wid - 1];
        int c = carry;
        int incl = c + blockoff + x;
        if (i < NN) { rp[i + 1] = incl; wp[i] = incl - v; }
        int total = wsum[15];
        __syncthreads();
        if (tid == 0) carry = c + total;
        __syncthreads();
    }
}

__global__ void k_scatter(const int* __restrict__ rows, const int* __restrict__ cols,
                          const float* __restrict__ vals, int* __restrict__ wp,
                          int2* __restrict__ edat) {
    int e = blockIdx.x * blockDim.x + threadIdx.x;
    if (e >= NNZS) return;
    int r = rows[e];
    int pos = atomicAdd(&wp[r], 1);
    edat[pos] = make_int2(cols[e], __float_as_int(vals[e]));
}

// ---------------- side[r] = sum_e val_e * ego[col_e]: one wave per row, lane = dim, no atomics
__global__ void k_spmm_csr(const int* __restrict__ rp, const int2* __restrict__ edat,
                           const float* __restrict__ ego, float* __restrict__ side) {
    int lane = threadIdx.x & 63;
    int wave = (blockIdx.x * blockDim.x + threadIdx.x) >> 6;
    int nw   = (gridDim.x * blockDim.x) >> 6;
    for (int r = wave; r < NN; r += nw) {
        int e0 = rp[r], e1 = rp[r + 1];
        float acc = 0.f;
        int e = e0;
        for (; e + 8 <= e1; e += 8) {
            int2 d[8];
#pragma unroll
            for (int j = 0; j < 8; ++j) d[j] = edat[e + j];
#pragma unroll
            for (int j = 0; j < 8; ++j)
                acc = fmaf(__int_as_float(d[j].y), ego[(size_t)d[j].x * DD + lane], acc);
        }
        for (; e < e1; ++e) {
            int2 d = edat[e];
            acc = fmaf(__int_as_float(d.y), ego[(size_t)d.x * DD + lane], acc);
        }
        side[(size_t)r * DD + lane] = acc;
    }
}

// ---------------- dense layer via MFMA: ego = leaky(side@WgT+bg) + leaky((ego*side)@WbT+bb)
__global__ __launch_bounds__(256) void k_dense(const float* __restrict__ side, float* __restrict__ ego,
                        const unsigned short* __restrict__ wg_bf,
                        const unsigned short* __restrict__ wb_bf,
                        const float* __restrict__ gcb, const float* __restrict__ bib,
                        unsigned short* __restrict__ allemb, int colofs) {
    int lane = threadIdx.x & 63;
    int wave = threadIdx.x >> 6;
    int n0 = (blockIdx.x * 4 + wave) * 16;
    int nrow = lane & 15;
    int kofs = (lane >> 4) * 8;

    short8 bg[4][2], bb[4][2];
#pragma unroll
    for (int nf = 0; nf < 4; ++nf)
#pragma unroll
        for (int kt = 0; kt < 2; ++kt) {
            bg[nf][kt] = *(const short8*)(wg_bf + (nf * 16 + nrow) * DD + kt * 32 + kofs);
            bb[nf][kt] = *(const short8*)(wb_bf + (nf * 16 + nrow) * DD + kt * 32 + kofs);
        }

    short8 a1[2], a2[2];
    const float* sp = side + (size_t)(n0 + nrow) * DD;
    const float* ep = ego  + (size_t)(n0 + nrow) * DD;
#pragma unroll
    for (int kt = 0; kt < 2; ++kt) {
        int o = kt * 32 + kofs;
#pragma unroll
        for (int j = 0; j < 8; ++j) {
            float s = sp[o + j];
            float e = ep[o + j];
            a1[kt][j] = (short)f2bf(s);
            a2[kt][j] = (short)f2bf(e * s);
        }
    }

    f32x4 acc1[4], acc2[4];
#pragma unroll
    for (int nf = 0; nf < 4; ++nf) { acc1[nf] = (f32x4){0,0,0,0}; acc2[nf] = (f32x4){0,0,0,0}; }
#pragma unroll
    for (int nf = 0; nf < 4; ++nf)
#pragma unroll
        for (int kt = 0; kt < 2; ++kt) {
            acc1[nf] = __builtin_amdgcn_mfma_f32_16x16x32_bf16(a1[kt], bg[nf][kt], acc1[nf], 0, 0, 0);
            acc2[nf] = __builtin_amdgcn_mfma_f32_16x16x32_bf16(a2[kt], bb[nf][kt], acc2[nf], 0, 0, 0);
        }

    int g = lane >> 4;
#pragma unroll
    for (int nf = 0; nf < 4; ++nf) {
        int o = nf * 16 + nrow;
        float b1 = gcb[o], b2 = bib[o];
#pragma unroll
        for (int r = 0; r < 4; ++r) {
            int node = n0 + g * 4 + r;
            float v1 = acc1[nf][r] + b1;
            float v2 = acc2[nf][r] + b2;
            v1 = v1 > 0.f ? v1 : 0.01f * v1;
            v2 = v2 > 0.f ? v2 : 0.01f * v2;
            float v = v1 + v2;
            ego[(size_t)node * DD + o] = v;
            allemb[(size_t)node * KD + colofs + o] = f2bf(v);
        }
    }
}

// ---------------- kernel A: per-row online (max, sum-exp) partials over a 640-col chunk
__global__ __launch_bounds__(256) void k_lse_part(const unsigned short* __restrict__ allemb,
                                                  float* __restrict__ pm, float* __restrict__ ps) {
    int id = blockIdx.x;
    int rowblk = id % RBLK;
    int chunk  = id / RBLK;
    int lane = threadIdx.x & 63;
    int wave = threadIdx.x >> 6;
    int r0 = rowblk * 128 + wave * 32;
    int c0 = chunk * ACHUNK;
    const unsigned short* A = allemb;
    const unsigned short* B = allemb + (size_t)NU * KD;
    int kofs = (lane >> 4) * 8;

    short8 a[2][6];
#pragma unroll
    for (int mi = 0; mi < 2; ++mi) {
        int ar = r0 + mi * 16 + (lane & 15);
        if (ar >= NU) ar = NU - 1;
#pragma unroll
        for (int kt = 0; kt < 6; ++kt)
            a[mi][kt] = *(const short8*)(A + (size_t)ar * KD + kt * 32 + kofs);
    }

    float m[2][4], s[2][4];
#pragma unroll
    for (int mi = 0; mi < 2; ++mi)
#pragma unroll
        for (int r = 0; r < 4; ++r) { m[mi][r] = -INFINITY; s[mi][r] = 0.f; }

    for (int t = 0; t < CTILES; ++t) {
        int c = c0 + t * 128;
        f32x4 acc[2][8];
#pragma unroll
        for (int mi = 0; mi < 2; ++mi)
#pragma unroll
            for (int nf = 0; nf < 8; ++nf) acc[mi][nf] = (f32x4){0.f, 0.f, 0.f, 0.f};
#pragma unroll
        for (int nf = 0; nf < 8; ++nf) {
            const unsigned short* bp = B + (size_t)(c + nf * 16 + (lane & 15)) * KD + kofs;
#pragma unroll
            for (int kt = 0; kt < 6; ++kt) {
                short8 b = *(const short8*)(bp + kt * 32);
                acc[0][nf] = __builtin_amdgcn_mfma_f32_16x16x32_bf16(a[0][kt], b, acc[0][nf], 0, 0, 0);
                acc[1][nf] = __builtin_amdgcn_mfma_f32_16x16x32_bf16(a[1][kt], b, acc[1][nf], 0, 0, 0);
            }
        }
#pragma unroll
        for (int mi = 0; mi < 2; ++mi)
#pragma unroll
            for (int r = 0; r < 4; ++r) {
                float lm = acc[mi][0][r];
#pragma unroll
                for (int nf = 1; nf < 8; ++nf) lm = fmaxf(lm, acc[mi][nf][r]);
                float nm = fmaxf(m[mi][r], lm);
                float p = 0.f;
#pragma unroll
                for (int nf = 0; nf < 8; ++nf) p += __expf(acc[mi][nf][r] - nm);
                s[mi][r] = s[mi][r] * __expf(m[mi][r] - nm) + p;
                m[mi][r] = nm;
            }
    }
#pragma unroll
    for (int mi = 0; mi < 2; ++mi)
#pragma unroll
        for (int r = 0; r < 4; ++r) {
            float mm = m[mi][r], ss = s[mi][r];
#pragma unroll
            for (int off = 1; off < 16; off <<= 1) {
                float om = __shfl_xor(mm, off, 64);
                float os = __shfl_xor(ss, off, 64);
                float nm = fmaxf(mm, om);
                ss = ss * __expf(mm - nm) + os * __expf(om - nm);
                mm = nm;
            }
            m[mi][r] = mm; s[mi][r] = ss;
        }
    if ((lane & 15) == 0) {
        int g = lane >> 4;
#pragma unroll
        for (int mi = 0; mi < 2; ++mi)
#pragma unroll
            for (int r = 0; r < 4; ++r) {
                int row = r0 + mi * 16 + g * 4 + r;
                if (row < NU) {
                    pm[chunk * NU + row] = m[mi][r];
                    ps[chunk * NU + row] = s[mi][r];
                }
            }
    }
}

// ---------------- combine partials: lse[r] = m + log(sum)
__global__ void k_lse_comb(const float* __restrict__ pm, const float* __restrict__ ps,
                           float* __restrict__ lse) {
    int r = blockIdx.x * blockDim.x + threadIdx.x;
    if (r >= NU) return;
    float m = -INFINITY;
    for (int c = 0; c < NCH; ++c) m = fmaxf(m, pm[c * NU + r]);
    float s = 0.f;
    for (int c = 0; c < NCH; ++c) s += ps[c * NU + r] * __expf(pm[c * NU + r] - m);
    lse[r] = m + __logf(s);
}

// ---------------- kernel B: recompute scores, write out = s - lse[row]
// colblk-FAST mapping: concurrent blocks span all 125 colblks -> writes cover the
// full 64KB row stride (no HBM channel camping); A tile reused by 125 consecutive blocks.
// Nontemporal stores keep the 500MB write stream out of L2.
__global__ __launch_bounds__(256) void k_out(const unsigned short* __restrict__ allemb,
                                             const float* __restrict__ lse, float* __restrict__ out) {
    __shared__ float tile[4][16][132];
    int id = blockIdx.x;
    int rowblk = id / CBLK;
    int colblk = id % CBLK;
    int lane = threadIdx.x & 63;
    int wave = threadIdx.x >> 6;
    int r0 = rowblk * 128 + wave * 32;
    int c0 = colblk * 128;
    const unsigned short* A = allemb;
    const unsigned short* B = allemb + (size_t)NU * KD;
    int kofs = (lane >> 4) * 8;
    int g = lane >> 4;

    short8 a[2][6];
#pragma unroll
    for (int mi = 0; mi < 2; ++mi) {
        int ar = r0 + mi * 16 + (lane & 15);
        if (ar >= NU) ar = NU - 1;
#pragma unroll
        for (int kt = 0; kt < 6; ++kt)
            a[mi][kt] = *(const short8*)(A + (size_t)ar * KD + kt * 32 + kofs);
    }

    f32x4 acc[2][8];
#pragma unroll
    for (int mi = 0; mi < 2; ++mi)
#pragma unroll
        for (int nf = 0; nf < 8; ++nf) acc[mi][nf] = (f32x4){0.f, 0.f, 0.f, 0.f};
#pragma unroll
    for (int nf = 0; nf < 8; ++nf) {
        const unsigned short* bp = B + (size_t)(c0 + nf * 16 + (lane & 15)) * KD + kofs;
#pragma unroll
        for (int kt = 0; kt < 6; ++kt) {
            short8 b = *(const short8*)(bp + kt * 32);
            acc[0][nf] = __builtin_amdgcn_mfma_f32_16x16x32_bf16(a[0][kt], b, acc[0][nf], 0, 0, 0);
            acc[1][nf] = __builtin_amdgcn_mfma_f32_16x16x32_bf16(a[1][kt], b, acc[1][nf], 0, 0, 0);
        }
    }

    float l4[2][4];
#pragma unroll
    for (int mi = 0; mi < 2; ++mi)
#pragma unroll
        for (int r = 0; r < 4; ++r) {
            int row = r0 + mi * 16 + g * 4 + r;
            l4[mi][r] = lse[row >= NU ? NU - 1 : row];
        }

#pragma unroll
    for (int mi = 0; mi < 2; ++mi) {
        int rowbase = r0 + mi * 16;
#pragma unroll
        for (int nf = 0; nf < 8; ++nf)
#pragma unroll
            for (int r = 0; r < 4; ++r)
                tile[wave][g * 4 + r][nf * 16 + (lane & 15)] = acc[mi][nf][r] - l4[mi][r];
#pragma unroll
        for (int it = 0; it < 8; ++it) {
            int idx = it * 64 + lane;
            int rr = idx >> 5;
            int cc = (idx & 31) * 4;
            int row = rowbase + rr;
            if (row < NU) {
                f32x4 v = *(const f32x4*)&tile[wave][rr][cc];
                __builtin_nontemporal_store(v, (f32x4*)&out[(size_t)row * NI + c0 + cc]);
            }
        }
    }
}

extern "C" void kernel_launch(void* const* d_in, const int* in_sizes, int n_in,
                              void* d_out, int out_size, void* d_ws, size_t ws_size,
                              hipStream_t stream) {
    const int*   uidx = (const int*)d_in[0];
    const int*   iidx = (const int*)d_in[1];
    const int*   arow = (const int*)d_in[2];
    const int*   acol = (const int*)d_in[3];
    const float* aval = (const float*)d_in[4];
    const float* ue   = (const float*)d_in[5];
    const float* ie   = (const float*)d_in[6];
    const float* gcW  = (const float*)d_in[7];
    const float* gcb  = (const float*)d_in[8];
    const float* biW  = (const float*)d_in[9];
    const float* bib  = (const float*)d_in[10];
    float* out = (float*)d_out;

    char* w = (char*)d_ws;
    float* ego  = (float*)w;                      w += (size_t)NN * DD * sizeof(float);
    float* side = (float*)w;                      w += (size_t)NN * DD * sizeof(float);
    unsigned short* allemb = (unsigned short*)w;  w += (size_t)NN * KD * sizeof(unsigned short);
    float* pm  = (float*)w;                       w += (size_t)NCH * NU * sizeof(float);
    float* ps  = (float*)w;                       w += (size_t)NCH * NU * sizeof(float);
    float* lse = (float*)w;                       w += (size_t)NU * sizeof(float);
    unsigned short* wbf = (unsigned short*)w;     w += (size_t)2 * NL * DD * DD * sizeof(unsigned short);
    int* cnt   = (int*)w;                         w += (size_t)NN * sizeof(int);
    int* rp    = (int*)w;                         w += (size_t)(NN + 2) * sizeof(int);  // +2 keeps edat 8B-aligned
    int* wp    = (int*)w;                         w += (size_t)NN * sizeof(int);
    int2* edat = (int2*)w;                        w += (size_t)NNZS * sizeof(int2);

    unsigned short* wg_bf = wbf;                  // [NL][64][64]
    unsigned short* wb_bf = wbf + NL * DD * DD;

    k_concat<<<(NN * DD + 255) / 256, 256, 0, stream>>>(uidx, iidx, ue, ie, gcW, biW,
                                                        ego, allemb, wbf, cnt);

    // CSR build (shared by both layers)
    k_hist<<<(NNZS + 255) / 256, 256, 0, stream>>>(arow, cnt);
    k_scan<<<1, 1024, 0, stream>>>(cnt, rp, wp);
    k_scatter<<<(NNZS + 255) / 256, 256, 0, stream>>>(arow, acol, aval, wp, edat);

    for (int l = 0; l < NL; ++l) {
        k_spmm_csr<<<3000, 256, 0, stream>>>(rp, edat, ego, side);
        k_dense<<<NN / 64, 256, 0, stream>>>(side, ego, wg_bf + l * DD * DD, wb_bf + l * DD * DD,
                                             gcb + l * DD, bib + l * DD, allemb, (l + 1) * DD);
    }

    k_lse_part<<<RBLK * NCH, 256, 0, stream>>>(allemb, pm, ps);
    k_lse_comb<<<(NU + 255) / 256, 256, 0, stream>>>(pm, ps, lse);
    k_out<<<RBLK * CBLK, 256, 0, stream>>>(allemb, lse, out);
}

// Round 7
// 646.488 us; speedup vs baseline: 1.6090x; 1.0195x over previous
//
#include <hip/hip_runtime.h>
#include <hip/hip_bf16.h>
#include <math.h>

#define NU   8000
#define NI   16000
#define NN   24000
#define DD   64
#define NL   2
#define NNZS 768000
#define KD   192        // 3 * 64 concat width
#define NCH  25         // column chunks for lse partials
#define ACHUNK 640      // 16000 / NCH
#define CTILES 5        // ACHUNK / 128
#define RBLK 63         // ceil(8000/128) row blocks

typedef __attribute__((ext_vector_type(8))) short  short8;
typedef __attribute__((ext_vector_type(4))) float  f32x4;
typedef __attribute__((ext_vector_type(4))) unsigned short us4;

__device__ __forceinline__ unsigned short f2bf(float x) {
    union { float f; unsigned int u; } v; v.f = x;
    unsigned int r = v.u + 0x7fff + ((v.u >> 16) & 1);   // round-nearest-even
    return (unsigned short)(r >> 16);
}
__device__ __forceinline__ float bf2f(unsigned short u) {
    union { unsigned int u; float f; } v; v.u = ((unsigned int)u) << 16;
    return v.f;
}

// ---------------- ego = concat(user_emb, item_emb); bf16 copy into all_emb[:, 0:64];
// zero CSR histogram; convert W stacks to bf16
__global__ void k_concat(const int* __restrict__ uidx, const int* __restrict__ iidx,
                         const float* __restrict__ ue, const float* __restrict__ ie,
                         const float* __restrict__ gcW, const float* __restrict__ biW,
                         float* __restrict__ ego, unsigned short* __restrict__ allemb,
                         unsigned short* __restrict__ wbf, int* __restrict__ cnt) {
    int t = blockIdx.x * blockDim.x + threadIdx.x;
    if (t < NN) cnt[t] = 0;
    if (t < NL * DD * DD) {
        wbf[t] = f2bf(gcW[t]);
        wbf[NL * DD * DD + t] = f2bf(biW[t]);
    }
    if (t >= NN * DD) return;
    int n = t >> 6, d = t & 63;
    float v = (n < NU) ? ue[uidx[n] * DD + d] : ie[iidx[n - NU] * DD + d];
    ego[t] = v;
    allemb[(size_t)n * KD + d] = f2bf(v);
}

// ---------------- CSR build: histogram -> shfl scan -> scatter
__global__ void k_hist(const int* __restrict__ rows, int* __restrict__ cnt) {
    int e = blockIdx.x * blockDim.x + threadIdx.x;
    if (e < NNZS) atomicAdd(&cnt[rows[e]], 1);
}

__global__ __launch_bounds__(1024) void k_scan(const int* __restrict__ cnt,
                                               int* __restrict__ rp, int* __restrict__ wp) {
    __shared__ int wsum[16];
    __shared__ int carry;
    int tid = threadIdx.x, lane = tid & 63, wid = tid >> 6;
    if (tid == 0) { carry = 0; rp[0] = 0; }
    __syncthreads();
    for (int base = 0; base < NN; base += 1024) {
        int i = base + tid;
        int v = (i < NN) ? cnt[i] : 0;
        int x = v;
#pragma unroll
        for (int off = 1; off < 64; off <<= 1) {
            int t = __shfl_up(x, off, 64);
            if (lane >= off) x += t;
        }
        if (lane == 63) wsum[wid] = x;
        __syncthreads();
        if (tid < 16) {
            int y = wsum[tid];
#pragma unroll
            for (int off = 1; off < 16; off <<= 1) {
                int t = __shfl_up(y, off, 64);
                if (tid >= off) y += t;
            }
            wsum[tid] = y;
        }
        __syncthreads();
        int blockoff = (wid == 0) ? 0 : wsum[wid - 1];
        int c = carry;
        int incl = c + blockoff + x;
        if (i < NN) { rp[i + 1] = incl; wp[i] = incl - v; }
        int total = wsum[15];
        __syncthreads();
        if (tid == 0) carry = c + total;
        __syncthreads();
    }
}

__global__ void k_scatter(const int* __restrict__ rows, const int* __restrict__ cols,
                          const float* __restrict__ vals, int* __restrict__ wp,
                          int2* __restrict__ edat) {
    int e = blockIdx.x * blockDim.x + threadIdx.x;
    if (e >= NNZS) return;
    int r = rows[e];
    int pos = atomicAdd(&wp[r], 1);
    edat[pos] = make_int2(cols[e], __float_as_int(vals[e]));
}

// ---------------- side[r] = sum_e val_e * feat[col_e]: bf16 gather from allemb (128 B/edge)
__global__ void k_spmm_csr(const int* __restrict__ rp, const int2* __restrict__ edat,
                           const unsigned short* __restrict__ feat, float* __restrict__ side) {
    int lane = threadIdx.x & 63;
    int wave = (blockIdx.x * blockDim.x + threadIdx.x) >> 6;
    int nw   = (gridDim.x * blockDim.x) >> 6;
    for (int r = wave; r < NN; r += nw) {
        int e0 = rp[r], e1 = rp[r + 1];
        float acc = 0.f;
        int e = e0;
        for (; e + 8 <= e1; e += 8) {
            int2 d[8];
#pragma unroll
            for (int j = 0; j < 8; ++j) d[j] = edat[e + j];
#pragma unroll
            for (int j = 0; j < 8; ++j)
                acc = fmaf(__int_as_float(d[j].y), bf2f(feat[(size_t)d[j].x * KD + lane]), acc);
        }
        for (; e < e1; ++e) {
            int2 d = edat[e];
            acc = fmaf(__int_as_float(d.y), bf2f(feat[(size_t)d.x * KD + lane]), acc);
        }
        side[(size_t)r * DD + lane] = acc;
    }
}

// ---------------- dense layer via MFMA
__global__ __launch_bounds__(256) void k_dense(const float* __restrict__ side, float* __restrict__ ego,
                        const unsigned short* __restrict__ wg_bf,
                        const unsigned short* __restrict__ wb_bf,
                        const float* __restrict__ gcb, const float* __restrict__ bib,
                        unsigned short* __restrict__ allemb, int colofs) {
    int lane = threadIdx.x & 63;
    int wave = threadIdx.x >> 6;
    int n0 = (blockIdx.x * 4 + wave) * 16;
    int nrow = lane & 15;
    int kofs = (lane >> 4) * 8;

    short8 bg[4][2], bb[4][2];
#pragma unroll
    for (int nf = 0; nf < 4; ++nf)
#pragma unroll
        for (int kt = 0; kt < 2; ++kt) {
            bg[nf][kt] = *(const short8*)(wg_bf + (nf * 16 + nrow) * DD + kt * 32 + kofs);
            bb[nf][kt] = *(const short8*)(wb_bf + (nf * 16 + nrow) * DD + kt * 32 + kofs);
        }

    short8 a1[2], a2[2];
    const float* sp = side + (size_t)(n0 + nrow) * DD;
    const float* ep = ego  + (size_t)(n0 + nrow) * DD;
#pragma unroll
    for (int kt = 0; kt < 2; ++kt) {
        int o = kt * 32 + kofs;
#pragma unroll
        for (int j = 0; j < 8; ++j) {
            float s = sp[o + j];
            float e = ep[o + j];
            a1[kt][j] = (short)f2bf(s);
            a2[kt][j] = (short)f2bf(e * s);
        }
    }

    f32x4 acc1[4], acc2[4];
#pragma unroll
    for (int nf = 0; nf < 4; ++nf) { acc1[nf] = (f32x4){0,0,0,0}; acc2[nf] = (f32x4){0,0,0,0}; }
#pragma unroll
    for (int nf = 0; nf < 4; ++nf)
#pragma unroll
        for (int kt = 0; kt < 2; ++kt) {
            acc1[nf] = __builtin_amdgcn_mfma_f32_16x16x32_bf16(a1[kt], bg[nf][kt], acc1[nf], 0, 0, 0);
            acc2[nf] = __builtin_amdgcn_mfma_f32_16x16x32_bf16(a2[kt], bb[nf][kt], acc2[nf], 0, 0, 0);
        }

    int g = lane >> 4;
#pragma unroll
    for (int nf = 0; nf < 4; ++nf) {
        int o = nf * 16 + nrow;
        float b1 = gcb[o], b2 = bib[o];
#pragma unroll
        for (int r = 0; r < 4; ++r) {
            int node = n0 + g * 4 + r;
            float v1 = acc1[nf][r] + b1;
            float v2 = acc2[nf][r] + b2;
            v1 = v1 > 0.f ? v1 : 0.01f * v1;
            v2 = v2 > 0.f ? v2 : 0.01f * v2;
            float v = v1 + v2;
            ego[(size_t)node * DD + o] = v;
            allemb[(size_t)node * KD + colofs + o] = f2bf(v);
        }
    }
}

// ---------------- single GEMM pass: bf16 score store + per-row online (m, sum-exp) partials
// grid RBLK*NCH (rowblk fast: consecutive blocks share the B chunk); block 256 = 4 waves x 32 rows
__global__ __launch_bounds__(256) void k_score_lse(const unsigned short* __restrict__ allemb,
                                                   unsigned short* __restrict__ scores,
                                                   float* __restrict__ pm, float* __restrict__ ps) {
    __shared__ float tile[4][16][132];
    int id = blockIdx.x;
    int rowblk = id % RBLK;
    int chunk  = id / RBLK;
    int lane = threadIdx.x & 63;
    int wave = threadIdx.x >> 6;
    int r0 = rowblk * 128 + wave * 32;
    int c0 = chunk * ACHUNK;
    const unsigned short* A = allemb;
    const unsigned short* B = allemb + (size_t)NU * KD;
    int kofs = (lane >> 4) * 8;
    int g = lane >> 4;

    short8 a[2][6];
#pragma unroll
    for (int mi = 0; mi < 2; ++mi) {
        int ar = r0 + mi * 16 + (lane & 15);
        if (ar >= NU) ar = NU - 1;
#pragma unroll
        for (int kt = 0; kt < 6; ++kt)
            a[mi][kt] = *(const short8*)(A + (size_t)ar * KD + kt * 32 + kofs);
    }

    float m[2][4], s[2][4];
#pragma unroll
    for (int mi = 0; mi < 2; ++mi)
#pragma unroll
        for (int r = 0; r < 4; ++r) { m[mi][r] = -INFINITY; s[mi][r] = 0.f; }

    for (int t = 0; t < CTILES; ++t) {
        int c = c0 + t * 128;
        f32x4 acc[2][8];
#pragma unroll
        for (int mi = 0; mi < 2; ++mi)
#pragma unroll
            for (int nf = 0; nf < 8; ++nf) acc[mi][nf] = (f32x4){0.f, 0.f, 0.f, 0.f};
#pragma unroll
        for (int nf = 0; nf < 8; ++nf) {
            const unsigned short* bp = B + (size_t)(c + nf * 16 + (lane & 15)) * KD + kofs;
#pragma unroll
            for (int kt = 0; kt < 6; ++kt) {
                short8 b = *(const short8*)(bp + kt * 32);
                acc[0][nf] = __builtin_amdgcn_mfma_f32_16x16x32_bf16(a[0][kt], b, acc[0][nf], 0, 0, 0);
                acc[1][nf] = __builtin_amdgcn_mfma_f32_16x16x32_bf16(a[1][kt], b, acc[1][nf], 0, 0, 0);
            }
        }
        // lane-local online update
#pragma unroll
        for (int mi = 0; mi < 2; ++mi)
#pragma unroll
            for (int r = 0; r < 4; ++r) {
                float lm = acc[mi][0][r];
#pragma unroll
                for (int nf = 1; nf < 8; ++nf) lm = fmaxf(lm, acc[mi][nf][r]);
                float nm = fmaxf(m[mi][r], lm);
                float p = 0.f;
#pragma unroll
                for (int nf = 0; nf < 8; ++nf) p += __expf(acc[mi][nf][r] - nm);
                s[mi][r] = s[mi][r] * __expf(m[mi][r] - nm) + p;
                m[mi][r] = nm;
            }
        // stage tile (wave-private LDS) and write coalesced bf16 scores
#pragma unroll
        for (int mi = 0; mi < 2; ++mi) {
            int rowbase = r0 + mi * 16;
#pragma unroll
            for (int nf = 0; nf < 8; ++nf)
#pragma unroll
                for (int r = 0; r < 4; ++r)
                    tile[wave][g * 4 + r][nf * 16 + (lane & 15)] = acc[mi][nf][r];
#pragma unroll
            for (int it = 0; it < 8; ++it) {
                int idx = it * 64 + lane;
                int rr = idx >> 5;
                int cc = (idx & 31) * 4;
                int row = rowbase + rr;
                if (row < NU) {
                    f32x4 v = *(const f32x4*)&tile[wave][rr][cc];
                    us4 o;
                    o[0] = f2bf(v[0]); o[1] = f2bf(v[1]); o[2] = f2bf(v[2]); o[3] = f2bf(v[3]);
                    __builtin_nontemporal_store(o, (us4*)&scores[(size_t)row * NI + c + cc]);
                }
            }
        }
    }
    // merge 16-lane groups once
#pragma unroll
    for (int mi = 0; mi < 2; ++mi)
#pragma unroll
        for (int r = 0; r < 4; ++r) {
            float mm = m[mi][r], ss = s[mi][r];
#pragma unroll
            for (int off = 1; off < 16; off <<= 1) {
                float om = __shfl_xor(mm, off, 64);
                float os = __shfl_xor(ss, off, 64);
                float nm = fmaxf(mm, om);
                ss = ss * __expf(mm - nm) + os * __expf(om - nm);
                mm = nm;
            }
            m[mi][r] = mm; s[mi][r] = ss;
        }
    if ((lane & 15) == 0) {
#pragma unroll
        for (int mi = 0; mi < 2; ++mi)
#pragma unroll
            for (int r = 0; r < 4; ++r) {
                int row = r0 + mi * 16 + g * 4 + r;
                if (row < NU) {
                    pm[chunk * NU + row] = m[mi][r];
                    ps[chunk * NU + row] = s[mi][r];
                }
            }
    }
}

// ---------------- combine partials: lse[r] = m + log(sum)
__global__ void k_lse_comb(const float* __restrict__ pm, const float* __restrict__ ps,
                           float* __restrict__ lse) {
    int r = blockIdx.x * blockDim.x + threadIdx.x;
    if (r >= NU) return;
    float m = -INFINITY;
    for (int c = 0; c < NCH; ++c) m = fmaxf(m, pm[c * NU + r]);
    float s = 0.f;
    for (int c = 0; c < NCH; ++c) s += ps[c * NU + r] * __expf(pm[c * NU + r] - m);
    lse[r] = m + __logf(s);
}

// ---------------- streaming epilogue: out = float(score_bf16) - lse[row]
__global__ __launch_bounds__(256) void k_sub(const unsigned short* __restrict__ scores,
                                             const float* __restrict__ lse,
                                             float* __restrict__ out) {
    const int CH = NI / 8;   // 2000 8-col chunks per row
    int stride = gridDim.x * blockDim.x;
    for (int ch = blockIdx.x * blockDim.x + threadIdx.x; ch < NU * CH; ch += stride) {
        int row = ch / CH;
        int col = (ch - row * CH) * 8;
        short8 sv = __builtin_nontemporal_load((const short8*)(scores + (size_t)row * NI + col));
        float l = lse[row];
        f32x4 o0, o1;
#pragma unroll
        for (int j = 0; j < 4; ++j) o0[j] = bf2f((unsigned short)sv[j]) - l;
#pragma unroll
        for (int j = 0; j < 4; ++j) o1[j] = bf2f((unsigned short)sv[4 + j]) - l;
        __builtin_nontemporal_store(o0, (f32x4*)&out[(size_t)row * NI + col]);
        __builtin_nontemporal_store(o1, (f32x4*)&out[(size_t)row * NI + col + 4]);
    }
}

extern "C" void kernel_launch(void* const* d_in, const int* in_sizes, int n_in,
                              void* d_out, int out_size, void* d_ws, size_t ws_size,
                              hipStream_t stream) {
    const int*   uidx = (const int*)d_in[0];
    const int*   iidx = (const int*)d_in[1];
    const int*   arow = (const int*)d_in[2];
    const int*   acol = (const int*)d_in[3];
    const float* aval = (const float*)d_in[4];
    const float* ue   = (const float*)d_in[5];
    const float* ie   = (const float*)d_in[6];
    const float* gcW  = (const float*)d_in[7];
    const float* gcb  = (const float*)d_in[8];
    const float* biW  = (const float*)d_in[9];
    const float* bib  = (const float*)d_in[10];
    float* out = (float*)d_out;

    char* w = (char*)d_ws;
    unsigned short* scores = (unsigned short*)w;  w += (size_t)NU * NI * sizeof(unsigned short);
    float* ego  = (float*)w;                      w += (size_t)NN * DD * sizeof(float);
    float* side = (float*)w;                      w += (size_t)NN * DD * sizeof(float);
    unsigned short* allemb = (unsigned short*)w;  w += (size_t)NN * KD * sizeof(unsigned short);
    float* pm  = (float*)w;                       w += (size_t)NCH * NU * sizeof(float);
    float* ps  = (float*)w;                       w += (size_t)NCH * NU * sizeof(float);
    float* lse = (float*)w;                       w += (size_t)NU * sizeof(float);
    unsigned short* wbf = (unsigned short*)w;     w += (size_t)2 * NL * DD * DD * sizeof(unsigned short);
    int* cnt   = (int*)w;                         w += (size_t)NN * sizeof(int);
    int* rp    = (int*)w;                         w += (size_t)(NN + 4) * sizeof(int);
    int* wp    = (int*)w;                         w += (size_t)NN * sizeof(int);
    int2* edat = (int2*)w;                        w += (size_t)NNZS * sizeof(int2);

    unsigned short* wg_bf = wbf;                  // [NL][64][64]
    unsigned short* wb_bf = wbf + NL * DD * DD;

    k_concat<<<(NN * DD + 255) / 256, 256, 0, stream>>>(uidx, iidx, ue, ie, gcW, biW,
                                                        ego, allemb, wbf, cnt);

    // CSR build (shared by both layers)
    k_hist<<<(NNZS + 255) / 256, 256, 0, stream>>>(arow, cnt);
    k_scan<<<1, 1024, 0, stream>>>(cnt, rp, wp);
    k_scatter<<<(NNZS + 255) / 256, 256, 0, stream>>>(arow, acol, aval, wp, edat);

    for (int l = 0; l < NL; ++l) {
        k_spmm_csr<<<3000, 256, 0, stream>>>(rp, edat, allemb + l * DD, side);
        k_dense<<<NN / 64, 256, 0, stream>>>(side, ego, wg_bf + l * DD * DD, wb_bf + l * DD * DD,
                                             gcb + l * DD, bib + l * DD, allemb, (l + 1) * DD);
    }

    k_score_lse<<<RBLK * NCH, 256, 0, stream>>>(allemb, scores, pm, ps);
    k_lse_comb<<<(NU + 255) / 256, 256, 0, stream>>>(pm, ps, lse);
    k_sub<<<2048, 256, 0, stream>>>(scores, lse, out);
}

// Round 8
// 496.984 us; speedup vs baseline: 2.0930x; 1.3008x over previous
//
#include <hip/hip_runtime.h>
#include <hip/hip_bf16.h>
#include <math.h>

#define NU   8000
#define NI   16000
#define NN   24000
#define DD   64
#define NL   2
#define NNZS 768000
#define KD   192        // 3 * 64 concat width
#define NCH  25         // column chunks for lse partials
#define ACHUNK 640      // 16000 / NCH
#define CTILES 5        // ACHUNK / 128
#define RBLK 63         // ceil(8000/128) row blocks
#define CBLK 125        // 16000/128 col blocks

typedef __attribute__((ext_vector_type(8))) short  short8;
typedef __attribute__((ext_vector_type(4))) float  f32x4;

__device__ __forceinline__ unsigned short f2bf(float x) {
    union { float f; unsigned int u; } v; v.f = x;
    unsigned int r = v.u + 0x7fff + ((v.u >> 16) & 1);   // round-nearest-even
    return (unsigned short)(r >> 16);
}
__device__ __forceinline__ float bf2f(unsigned short u) {
    union { unsigned int u; float f; } v; v.u = ((unsigned int)u) << 16;
    return v.f;
}

// B-tile LDS layout: slot idx for (nf,kt,g,r16) = ((kt*8+nf)*4+g)*16+r16, XOR'd by (g+4kt)&7
// -> staging writes ~3-way bank alias; fragment reads are lane-consecutive (conflict-free b128).
__device__ __forceinline__ int bslot(int nf, int kt, int g, int r16) {
    return ((((kt * 8 + nf) * 4 + g) * 16) + r16) ^ ((g + 4 * kt) & 7);
}

// ---------------- ego = concat(user_emb, item_emb); bf16 copy into all_emb[:, 0:64];
// zero CSR histogram; convert W stacks to bf16
__global__ void k_concat(const int* __restrict__ uidx, const int* __restrict__ iidx,
                         const float* __restrict__ ue, const float* __restrict__ ie,
                         const float* __restrict__ gcW, const float* __restrict__ biW,
                         float* __restrict__ ego, unsigned short* __restrict__ allemb,
                         unsigned short* __restrict__ wbf, int* __restrict__ cnt) {
    int t = blockIdx.x * blockDim.x + threadIdx.x;
    if (t < NN) cnt[t] = 0;
    if (t < NL * DD * DD) {
        wbf[t] = f2bf(gcW[t]);
        wbf[NL * DD * DD + t] = f2bf(biW[t]);
    }
    if (t >= NN * DD) return;
    int n = t >> 6, d = t & 63;
    float v = (n < NU) ? ue[uidx[n] * DD + d] : ie[iidx[n - NU] * DD + d];
    ego[t] = v;
    allemb[(size_t)n * KD + d] = f2bf(v);
}

// ---------------- CSR build: histogram -> shfl scan -> scatter
__global__ void k_hist(const int* __restrict__ rows, int* __restrict__ cnt) {
    int e = blockIdx.x * blockDim.x + threadIdx.x;
    if (e < NNZS) atomicAdd(&cnt[rows[e]], 1);
}

__global__ __launch_bounds__(1024) void k_scan(const int* __restrict__ cnt,
                                               int* __restrict__ rp, int* __restrict__ wp) {
    __shared__ int wsum[16];
    __shared__ int carry;
    int tid = threadIdx.x, lane = tid & 63, wid = tid >> 6;
    if (tid == 0) { carry = 0; rp[0] = 0; }
    __syncthreads();
    for (int base = 0; base < NN; base += 1024) {
        int i = base + tid;
        int v = (i < NN) ? cnt[i] : 0;
        int x = v;
#pragma unroll
        for (int off = 1; off < 64; off <<= 1) {
            int t = __shfl_up(x, off, 64);
            if (lane >= off) x += t;
        }
        if (lane == 63) wsum[wid] = x;
        __syncthreads();
        if (tid < 16) {
            int y = wsum[tid];
#pragma unroll
            for (int off = 1; off < 16; off <<= 1) {
                int t = __shfl_up(y, off, 64);
                if (tid >= off) y += t;
            }
            wsum[tid] = y;
        }
        __syncthreads();
        int blockoff = (wid == 0) ? 0 : wsum[wid - 1];
        int c = carry;
        int incl = c + blockoff + x;
        if (i < NN) { rp[i + 1] = incl; wp[i] = incl - v; }
        int total = wsum[15];
        __syncthreads();
        if (tid == 0) carry = c + total;
        __syncthreads();
    }
}

__global__ void k_scatter(const int* __restrict__ rows, const int* __restrict__ cols,
                          const float* __restrict__ vals, int* __restrict__ wp,
                          int2* __restrict__ edat) {
    int e = blockIdx.x * blockDim.x + threadIdx.x;
    if (e >= NNZS) return;
    int r = rows[e];
    int pos = atomicAdd(&wp[r], 1);
    edat[pos] = make_int2(cols[e], __float_as_int(vals[e]));
}

// ---------------- side[r] = sum_e val_e * feat[col_e]: bf16 gather from allemb (128 B/edge)
__global__ void k_spmm_csr(const int* __restrict__ rp, const int2* __restrict__ edat,
                           const unsigned short* __restrict__ feat, float* __restrict__ side) {
    int lane = threadIdx.x & 63;
    int wave = (blockIdx.x * blockDim.x + threadIdx.x) >> 6;
    int nw   = (gridDim.x * blockDim.x) >> 6;
    for (int r = wave; r < NN; r += nw) {
        int e0 = rp[r], e1 = rp[r + 1];
        float acc = 0.f;
        int e = e0;
        for (; e + 8 <= e1; e += 8) {
            int2 d[8];
#pragma unroll
            for (int j = 0; j < 8; ++j) d[j] = edat[e + j];
#pragma unroll
            for (int j = 0; j < 8; ++j)
                acc = fmaf(__int_as_float(d[j].y), bf2f(feat[(size_t)d[j].x * KD + lane]), acc);
        }
        for (; e < e1; ++e) {
            int2 d = edat[e];
            acc = fmaf(__int_as_float(d.y), bf2f(feat[(size_t)d.x * KD + lane]), acc);
        }
        side[(size_t)r * DD + lane] = acc;
    }
}

// ---------------- dense layer via MFMA
__global__ __launch_bounds__(256) void k_dense(const float* __restrict__ side, float* __restrict__ ego,
                        const unsigned short* __restrict__ wg_bf,
                        const unsigned short* __restrict__ wb_bf,
                        const float* __restrict__ gcb, const float* __restrict__ bib,
                        unsigned short* __restrict__ allemb, int colofs) {
    int lane = threadIdx.x & 63;
    int wave = threadIdx.x >> 6;
    int n0 = (blockIdx.x * 4 + wave) * 16;
    int nrow = lane & 15;
    int kofs = (lane >> 4) * 8;

    short8 bg[4][2], bb[4][2];
#pragma unroll
    for (int nf = 0; nf < 4; ++nf)
#pragma unroll
        for (int kt = 0; kt < 2; ++kt) {
            bg[nf][kt] = *(const short8*)(wg_bf + (nf * 16 + nrow) * DD + kt * 32 + kofs);
            bb[nf][kt] = *(const short8*)(wb_bf + (nf * 16 + nrow) * DD + kt * 32 + kofs);
        }

    short8 a1[2], a2[2];
    const float* sp = side + (size_t)(n0 + nrow) * DD;
    const float* ep = ego  + (size_t)(n0 + nrow) * DD;
#pragma unroll
    for (int kt = 0; kt < 2; ++kt) {
        int o = kt * 32 + kofs;
#pragma unroll
        for (int j = 0; j < 8; ++j) {
            float s = sp[o + j];
            float e = ep[o + j];
            a1[kt][j] = (short)f2bf(s);
            a2[kt][j] = (short)f2bf(e * s);
        }
    }

    f32x4 acc1[4], acc2[4];
#pragma unroll
    for (int nf = 0; nf < 4; ++nf) { acc1[nf] = (f32x4){0,0,0,0}; acc2[nf] = (f32x4){0,0,0,0}; }
#pragma unroll
    for (int nf = 0; nf < 4; ++nf)
#pragma unroll
        for (int kt = 0; kt < 2; ++kt) {
            acc1[nf] = __builtin_amdgcn_mfma_f32_16x16x32_bf16(a1[kt], bg[nf][kt], acc1[nf], 0, 0, 0);
            acc2[nf] = __builtin_amdgcn_mfma_f32_16x16x32_bf16(a2[kt], bb[nf][kt], acc2[nf], 0, 0, 0);
        }

    int g = lane >> 4;
#pragma unroll
    for (int nf = 0; nf < 4; ++nf) {
        int o = nf * 16 + nrow;
        float b1 = gcb[o], b2 = bib[o];
#pragma unroll
        for (int r = 0; r < 4; ++r) {
            int node = n0 + g * 4 + r;
            float v1 = acc1[nf][r] + b1;
            float v2 = acc2[nf][r] + b2;
            v1 = v1 > 0.f ? v1 : 0.01f * v1;
            v2 = v2 > 0.f ? v2 : 0.01f * v2;
            float v = v1 + v2;
            ego[(size_t)node * DD + o] = v;
            allemb[(size_t)node * KD + colofs + o] = f2bf(v);
        }
    }
}

// ---------------- kernel A: online (m, sum-exp) partials over a 640-col chunk,
// B subtiles LDS-staged (coalesced global, conflict-free ds_read_b128 fragments)
__global__ __launch_bounds__(256) void k_lse_part(const unsigned short* __restrict__ allemb,
                                                  float* __restrict__ pm, float* __restrict__ ps) {
    __shared__ short8 Bs[3072];   // 49152 B: 128 rows x 192 cols bf16, permuted
    int id = blockIdx.x;
    int rowblk = id % RBLK;
    int chunk  = id / RBLK;
    int tid = threadIdx.x;
    int lane = tid & 63;
    int wave = tid >> 6;
    int r0 = rowblk * 128 + wave * 32;
    int c0 = chunk * ACHUNK;
    const unsigned short* A = allemb;
    const unsigned short* B = allemb + (size_t)NU * KD;
    int kofs = (lane >> 4) * 8;
    int g = lane >> 4;

    short8 a[2][6];
#pragma unroll
    for (int mi = 0; mi < 2; ++mi) {
        int ar = r0 + mi * 16 + (lane & 15);
        if (ar >= NU) ar = NU - 1;
#pragma unroll
        for (int kt = 0; kt < 6; ++kt)
            a[mi][kt] = *(const short8*)(A + (size_t)ar * KD + kt * 32 + kofs);
    }

    float m[2][4], s[2][4];
#pragma unroll
    for (int mi = 0; mi < 2; ++mi)
#pragma unroll
        for (int r = 0; r < 4; ++r) { m[mi][r] = -INFINITY; s[mi][r] = 0.f; }

    for (int t = 0; t < CTILES; ++t) {
        const unsigned short* Bt = B + (size_t)(c0 + t * 128) * KD;
        __syncthreads();   // previous subtile's reads complete
#pragma unroll
        for (int i = 0; i < 12; ++i) {
            int mm = i * 256 + tid;              // 3072 16B-chunks
            int r = mm / 24, c = mm - r * 24;    // row in tile, 16B chunk in row
            int kt = c >> 2, gg = c & 3;
            Bs[bslot(r >> 4, kt, gg, r & 15)] = *(const short8*)(Bt + (size_t)r * KD + c * 8);
        }
        __syncthreads();

        f32x4 acc[2][8];
#pragma unroll
        for (int mi = 0; mi < 2; ++mi)
#pragma unroll
            for (int nf = 0; nf < 8; ++nf) acc[mi][nf] = (f32x4){0.f, 0.f, 0.f, 0.f};
#pragma unroll
        for (int nf = 0; nf < 8; ++nf)
#pragma unroll
            for (int kt = 0; kt < 6; ++kt) {
                short8 b = Bs[bslot(nf, kt, g, lane & 15)];
                acc[0][nf] = __builtin_amdgcn_mfma_f32_16x16x32_bf16(a[0][kt], b, acc[0][nf], 0, 0, 0);
                acc[1][nf] = __builtin_amdgcn_mfma_f32_16x16x32_bf16(a[1][kt], b, acc[1][nf], 0, 0, 0);
            }
#pragma unroll
        for (int mi = 0; mi < 2; ++mi)
#pragma unroll
            for (int r = 0; r < 4; ++r) {
                float lm = acc[mi][0][r];
#pragma unroll
                for (int nf = 1; nf < 8; ++nf) lm = fmaxf(lm, acc[mi][nf][r]);
                float nm = fmaxf(m[mi][r], lm);
                float p = 0.f;
#pragma unroll
                for (int nf = 0; nf < 8; ++nf) p += __expf(acc[mi][nf][r] - nm);
                s[mi][r] = s[mi][r] * __expf(m[mi][r] - nm) + p;
                m[mi][r] = nm;
            }
    }
#pragma unroll
    for (int mi = 0; mi < 2; ++mi)
#pragma unroll
        for (int r = 0; r < 4; ++r) {
            float mm = m[mi][r], ss = s[mi][r];
#pragma unroll
            for (int off = 1; off < 16; off <<= 1) {
                float om = __shfl_xor(mm, off, 64);
                float os = __shfl_xor(ss, off, 64);
                float nm = fmaxf(mm, om);
                ss = ss * __expf(mm - nm) + os * __expf(om - nm);
                mm = nm;
            }
            m[mi][r] = mm; s[mi][r] = ss;
        }
    if ((lane & 15) == 0) {
#pragma unroll
        for (int mi = 0; mi < 2; ++mi)
#pragma unroll
            for (int r = 0; r < 4; ++r) {
                int row = r0 + mi * 16 + g * 4 + r;
                if (row < NU) {
                    pm[chunk * NU + row] = m[mi][r];
                    ps[chunk * NU + row] = s[mi][r];
                }
            }
    }
}

// ---------------- combine partials: lse[r] = m + log(sum)
__global__ void k_lse_comb(const float* __restrict__ pm, const float* __restrict__ ps,
                           float* __restrict__ lse) {
    int r = blockIdx.x * blockDim.x + threadIdx.x;
    if (r >= NU) return;
    float m = -INFINITY;
    for (int c = 0; c < NCH; ++c) m = fmaxf(m, pm[c * NU + r]);
    float s = 0.f;
    for (int c = 0; c < NCH; ++c) s += ps[c * NU + r] * __expf(pm[c * NU + r] - m);
    lse[r] = m + __logf(s);
}

// ---------------- kernel B: recompute scores (B LDS-staged), out = s - lse[row]
// colblk-fast; LDS B buffer reused for the output staging tile after MFMAs.
__global__ __launch_bounds__(256) void k_out(const unsigned short* __restrict__ allemb,
                                             const float* __restrict__ lse, float* __restrict__ out) {
    __shared__ short8 Bs[3072];   // 49152 B; later reused as float tile[4][16][132] (33792 B)
    int id = blockIdx.x;
    int rowblk = id / CBLK;
    int colblk = id % CBLK;
    int tid = threadIdx.x;
    int lane = tid & 63;
    int wave = tid >> 6;
    int r0 = rowblk * 128 + wave * 32;
    int c0 = colblk * 128;
    const unsigned short* A = allemb;
    const unsigned short* B = allemb + (size_t)NU * KD;
    int kofs = (lane >> 4) * 8;
    int g = lane >> 4;

    // stage B tile
    const unsigned short* Bt = B + (size_t)c0 * KD;
#pragma unroll
    for (int i = 0; i < 12; ++i) {
        int mm = i * 256 + tid;
        int r = mm / 24, c = mm - r * 24;
        int kt = c >> 2, gg = c & 3;
        Bs[bslot(r >> 4, kt, gg, r & 15)] = *(const short8*)(Bt + (size_t)r * KD + c * 8);
    }

    short8 a[2][6];
#pragma unroll
    for (int mi = 0; mi < 2; ++mi) {
        int ar = r0 + mi * 16 + (lane & 15);
        if (ar >= NU) ar = NU - 1;
#pragma unroll
        for (int kt = 0; kt < 6; ++kt)
            a[mi][kt] = *(const short8*)(A + (size_t)ar * KD + kt * 32 + kofs);
    }
    float l4[2][4];
#pragma unroll
    for (int mi = 0; mi < 2; ++mi)
#pragma unroll
        for (int r = 0; r < 4; ++r) {
            int row = r0 + mi * 16 + g * 4 + r;
            l4[mi][r] = lse[row >= NU ? NU - 1 : row];
        }
    __syncthreads();

    f32x4 acc[2][8];
#pragma unroll
    for (int mi = 0; mi < 2; ++mi)
#pragma unroll
        for (int nf = 0; nf < 8; ++nf) acc[mi][nf] = (f32x4){0.f, 0.f, 0.f, 0.f};
#pragma unroll
    for (int nf = 0; nf < 8; ++nf)
#pragma unroll
        for (int kt = 0; kt < 6; ++kt) {
            short8 b = Bs[bslot(nf, kt, g, lane & 15)];
            acc[0][nf] = __builtin_amdgcn_mfma_f32_16x16x32_bf16(a[0][kt], b, acc[0][nf], 0, 0, 0);
            acc[1][nf] = __builtin_amdgcn_mfma_f32_16x16x32_bf16(a[1][kt], b, acc[1][nf], 0, 0, 0);
        }
    __syncthreads();   // all B reads done -> reuse LDS as output tile

    float* tilef = (float*)Bs;                 // [4][16][132]
    float* tW = tilef + wave * 16 * 132;
#pragma unroll
    for (int mi = 0; mi < 2; ++mi) {
        int rowbase = r0 + mi * 16;
#pragma unroll
        for (int nf = 0; nf < 8; ++nf)
#pragma unroll
            for (int r = 0; r < 4; ++r)
                tW[(g * 4 + r) * 132 + nf * 16 + (lane & 15)] = acc[mi][nf][r] - l4[mi][r];
#pragma unroll
        for (int it = 0; it < 8; ++it) {
            int idx = it * 64 + lane;
            int rr = idx >> 5;
            int cc = (idx & 31) * 4;
            int row = rowbase + rr;
            if (row < NU) {
                f32x4 v = *(const f32x4*)&tW[rr * 132 + cc];
                __builtin_nontemporal_store(v, (f32x4*)&out[(size_t)row * NI + c0 + cc]);
            }
        }
    }
}

extern "C" void kernel_launch(void* const* d_in, const int* in_sizes, int n_in,
                              void* d_out, int out_size, void* d_ws, size_t ws_size,
                              hipStream_t stream) {
    const int*   uidx = (const int*)d_in[0];
    const int*   iidx = (const int*)d_in[1];
    const int*   arow = (const int*)d_in[2];
    const int*   acol = (const int*)d_in[3];
    const float* aval = (const float*)d_in[4];
    const float* ue   = (const float*)d_in[5];
    const float* ie   = (const float*)d_in[6];
    const float* gcW  = (const float*)d_in[7];
    const float* gcb  = (const float*)d_in[8];
    const float* biW  = (const float*)d_in[9];
    const float* bib  = (const float*)d_in[10];
    float* out = (float*)d_out;

    char* w = (char*)d_ws;
    float* ego  = (float*)w;                      w += (size_t)NN * DD * sizeof(float);
    float* side = (float*)w;                      w += (size_t)NN * DD * sizeof(float);
    unsigned short* allemb = (unsigned short*)w;  w += (size_t)NN * KD * sizeof(unsigned short);
    float* pm  = (float*)w;                       w += (size_t)NCH * NU * sizeof(float);
    float* ps  = (float*)w;                       w += (size_t)NCH * NU * sizeof(float);
    float* lse = (float*)w;                       w += (size_t)NU * sizeof(float);
    unsigned short* wbf = (unsigned short*)w;     w += (size_t)2 * NL * DD * DD * sizeof(unsigned short);
    int* cnt   = (int*)w;                         w += (size_t)NN * sizeof(int);
    int* rp    = (int*)w;                         w += (size_t)(NN + 4) * sizeof(int);
    int* wp    = (int*)w;                         w += (size_t)NN * sizeof(int);
    int2* edat = (int2*)w;                        w += (size_t)NNZS * sizeof(int2);

    unsigned short* wg_bf = wbf;                  // [NL][64][64]
    unsigned short* wb_bf = wbf + NL * DD * DD;

    k_concat<<<(NN * DD + 255) / 256, 256, 0, stream>>>(uidx, iidx, ue, ie, gcW, biW,
                                                        ego, allemb, wbf, cnt);

    // CSR build (shared by both layers)
    k_hist<<<(NNZS + 255) / 256, 256, 0, stream>>>(arow, cnt);
    k_scan<<<1, 1024, 0, stream>>>(cnt, rp, wp);
    k_scatter<<<(NNZS + 255) / 256, 256, 0, stream>>>(arow, acol, aval, wp, edat);

    for (int l = 0; l < NL; ++l) {
        k_spmm_csr<<<3000, 256, 0, stream>>>(rp, edat, allemb + l * DD, side);
        k_dense<<<NN / 64, 256, 0, stream>>>(side, ego, wg_bf + l * DD * DD, wb_bf + l * DD * DD,
                                             gcb + l * DD, bib + l * DD, allemb, (l + 1) * DD);
    }

    k_lse_part<<<RBLK * NCH, 256, 0, stream>>>(allemb, pm, ps);
    k_lse_comb<<<(NU + 255) / 256, 256, 0, stream>>>(pm, ps, lse);
    k_out<<<RBLK * CBLK, 256, 0, stream>>>(allemb, lse, out);
}